// Round 2
// baseline (3805.655 us; speedup 1.0000x reference)
//
#include <hip/hip_runtime.h>
#include <math.h>

#define B_ 8
#define N_ 4096
#define C_ 512
#define H_ 8
#define D_ 64
#define M_ 16
#define BN_TOK (B_*N_)
#define TAU_ 0.1f

__device__ __forceinline__ float wave_reduce_sum(float v){
  #pragma unroll
  for (int o = 32; o > 0; o >>= 1) v += __shfl_xor(v, o);
  return v;
}

// ---------------- generic tiled GEMM: C_f32 = A_f32 * B_f32 ----------------
__global__ __launch_bounds__(256) void gemm_ff(const float* __restrict__ A, const float* __restrict__ Bm,
                         float* __restrict__ C, int M, int Ncols, int K,
                         int lda, int ldb, int ldc) {
  __shared__ float As[16][65];
  __shared__ float Bs[16][65];
  const int tx = threadIdx.x & 15, ty = threadIdx.x >> 4;
  const int bm = blockIdx.x * 64, bn = blockIdx.y * 64;
  float acc[4][4] = {};
  for (int k0 = 0; k0 < K; k0 += 16) {
    for (int i = threadIdx.x; i < 1024; i += 256) {
      int m = i >> 4, k = i & 15;
      As[k][m] = A[(size_t)(bm+m)*lda + k0 + k];
    }
    for (int i = threadIdx.x; i < 1024; i += 256) {
      int k = i >> 6, n = i & 63;
      Bs[k][n] = Bm[(size_t)(k0+k)*ldb + bn + n];
    }
    __syncthreads();
    #pragma unroll
    for (int k = 0; k < 16; ++k) {
      float a[4], b[4];
      #pragma unroll
      for (int i=0;i<4;++i) a[i] = As[k][ty*4+i];
      #pragma unroll
      for (int j=0;j<4;++j) b[j] = Bs[k][tx*4+j];
      #pragma unroll
      for (int i=0;i<4;++i)
        #pragma unroll
        for (int j=0;j<4;++j) acc[i][j] = fmaf(a[i], b[j], acc[i][j]);
    }
    __syncthreads();
  }
  for (int i=0;i<4;++i)
    for (int j=0;j<4;++j)
      C[(size_t)(bm+ty*4+i)*ldc + bn + tx*4 + j] = acc[i][j];
}

// ---------- GEMM + bias epilogue (final proj) ----------
__global__ __launch_bounds__(256) void gemm_ff_bias(const float* __restrict__ A, const float* __restrict__ Bm,
                              const float* __restrict__ bias, float* __restrict__ C,
                              int M, int Ncols, int K, int lda, int ldb, int ldc) {
  __shared__ float As[16][65];
  __shared__ float Bs[16][65];
  const int tx = threadIdx.x & 15, ty = threadIdx.x >> 4;
  const int bm = blockIdx.x * 64, bn = blockIdx.y * 64;
  float acc[4][4] = {};
  for (int k0 = 0; k0 < K; k0 += 16) {
    for (int i = threadIdx.x; i < 1024; i += 256) {
      int m = i >> 4, k = i & 15;
      As[k][m] = A[(size_t)(bm+m)*lda + k0 + k];
    }
    for (int i = threadIdx.x; i < 1024; i += 256) {
      int k = i >> 6, n = i & 63;
      Bs[k][n] = Bm[(size_t)(k0+k)*ldb + bn + n];
    }
    __syncthreads();
    #pragma unroll
    for (int k = 0; k < 16; ++k) {
      float a[4], b[4];
      #pragma unroll
      for (int i=0;i<4;++i) a[i] = As[k][ty*4+i];
      #pragma unroll
      for (int j=0;j<4;++j) b[j] = Bs[k][tx*4+j];
      #pragma unroll
      for (int i=0;i<4;++i)
        #pragma unroll
        for (int j=0;j<4;++j) acc[i][j] = fmaf(a[i], b[j], acc[i][j]);
    }
    __syncthreads();
  }
  for (int i=0;i<4;++i)
    for (int j=0;j<4;++j)
      C[(size_t)(bm+ty*4+i)*ldc + bn + tx*4 + j] = acc[i][j] + bias[bn + tx*4 + j];
}

// ---------------- router top-k + masked softmax ----------------
__global__ __launch_bounds__(256) void router_topk(const float* __restrict__ logits,
                            const float* __restrict__ b_rspec, const float* __restrict__ b_rspat,
                            float* __restrict__ r_spec, float* __restrict__ r_spat) {
  int t = blockIdx.x * blockDim.x + threadIdx.x;
  if (t >= BN_TOK * H_ * 2) return;
  int route = t & 1, h = (t >> 1) & 7, bn = t >> 4;
  int b = bn >> 12, n = bn & 4095;
  const float* lg = logits + (size_t)bn*256 + route*128 + h*16;
  const float* bias = (route ? b_rspat : b_rspec) + h*16;
  float v[16];
  #pragma unroll
  for (int m=0;m<16;++m) v[m] = lg[m] + bias[m];
  float m1=-1e30f, m2=-1e30f, m3=-1e30f;
  #pragma unroll
  for (int m=0;m<16;++m){
    float x=v[m];
    if (x>m1){m3=m2;m2=m1;m1=x;}
    else if (x>m2){m3=m2;m2=x;}
    else if (x>m3){m3=x;}
  }
  float S=0.f, Sm=0.f, e[16];
  #pragma unroll
  for (int m=0;m<16;++m){ e[m]=expf(v[m]-m1); S+=e[m]; if (v[m]>=m3) Sm+=e[m]; }
  float denom = fmaxf(Sm/S, 1e-6f);
  float inv = 1.f/(S*denom);
  float* r = (route ? r_spat : r_spec) + (((size_t)b*H_ + h)*N_ + n)*16;
  #pragma unroll
  for (int m=0;m<16;++m) r[m] = (v[m] >= m3) ? e[m]*inv : 0.f;
}

// ------------- per-(b,h): K_eff -> softmax over n -> context = P^T V -------------
__global__ __launch_bounds__(256) void context_kernel(const float* __restrict__ r_spec, const float* __restrict__ r_spat,
                               const float* __restrict__ K_spec, const float* __restrict__ K_spat,
                               const float* __restrict__ qv, float* __restrict__ ctx_out) {
  const int b = blockIdx.x >> 3, h = blockIdx.x & 7;
  const int tid = threadIdx.x;
  __shared__ float Ks[16][64], Kt[16][64];
  __shared__ float rs[64][17], rt[64][17];
  __shared__ float pb[64][65];
  __shared__ float vs[64][65];
  __shared__ float red[256];
  __shared__ float maxd[64], Zd[64];
  for (int i = tid; i < 1024; i += 256) {
    Ks[i>>6][i&63] = K_spec[h*1024 + i];
    Kt[i>>6][i&63] = K_spat[h*1024 + i];
  }
  const float* rsg = r_spec + ((size_t)b*H_ + h)*N_*16;
  const float* rtg = r_spat + ((size_t)b*H_ + h)*N_*16;
  const int d = tid & 63, nl = tid >> 6;
  float mx = -1e30f;
  __syncthreads();
  // pass 1: per-d max of K_eff over n
  for (int n0 = 0; n0 < N_; n0 += 64) {
    for (int i = tid; i < 1024; i += 256) {
      rs[i>>4][i&15] = rsg[n0*16 + i];
      rt[i>>4][i&15] = rtg[n0*16 + i];
    }
    __syncthreads();
    for (int nn = nl; nn < 64; nn += 4) {
      float acc = 0.f;
      #pragma unroll
      for (int m=0;m<16;++m) acc += rs[nn][m]*Ks[m][d] + rt[nn][m]*Kt[m][d];
      mx = fmaxf(mx, acc);
    }
    __syncthreads();
  }
  red[tid] = mx; __syncthreads();
  if (tid < 64) maxd[tid] = fmaxf(fmaxf(red[tid],red[tid+64]), fmaxf(red[tid+128],red[tid+192]));
  __syncthreads();
  // pass 2: Z and unnormalized context
  float zacc = 0.f;
  float cacc[16];
  #pragma unroll
  for (int j=0;j<16;++j) cacc[j]=0.f;
  const int dd = tid >> 2, es = (tid & 3) * 16;
  const float* vg = qv + 512 + h*64;  // v columns of qv
  for (int n0 = 0; n0 < N_; n0 += 64) {
    for (int i = tid; i < 1024; i += 256) {
      rs[i>>4][i&15] = rsg[n0*16 + i];
      rt[i>>4][i&15] = rtg[n0*16 + i];
    }
    for (int i = tid; i < 4096; i += 256) {
      int nn = i >> 6, e = i & 63;
      vs[nn][e] = vg[(size_t)(b*N_ + n0 + nn)*1024 + e];
    }
    __syncthreads();
    for (int nn = nl; nn < 64; nn += 4) {
      float acc = 0.f;
      #pragma unroll
      for (int m=0;m<16;++m) acc += rs[nn][m]*Ks[m][d] + rt[nn][m]*Kt[m][d];
      float p = expf(acc - maxd[d]);
      pb[nn][d] = p;
      zacc += p;
    }
    __syncthreads();
    for (int nn = 0; nn < 64; ++nn) {
      float pv = pb[nn][dd];
      #pragma unroll
      for (int j=0;j<16;++j) cacc[j] = fmaf(pv, vs[nn][es+j], cacc[j]);
    }
    __syncthreads();
  }
  red[tid] = zacc; __syncthreads();
  if (tid < 64) Zd[tid] = red[tid]+red[tid+64]+red[tid+128]+red[tid+192];
  __syncthreads();
  float invZ = 1.f / Zd[dd];
  float* co = ctx_out + (((size_t)b*H_ + h)*64 + dd)*64 + es;
  #pragma unroll
  for (int j=0;j<16;++j) co[j] = cacc[j]*invZ;
}

// ---------------- out_attn[b,n,h*64+e] = q[b,n,h,:] @ context[b,h] ----------------
__global__ __launch_bounds__(256) void attn_out_kernel(const float* __restrict__ qv, const float* __restrict__ ctx,
                                float* __restrict__ out_attn) {
  int blk = blockIdx.x;
  int nt = blk & 63, h = (blk >> 6) & 7, b = blk >> 9;
  int n0 = nt * 64;
  __shared__ float cs[64][65];
  __shared__ float qs[64][65];
  int tid = threadIdx.x;
  const float* cg = ctx + ((size_t)b*H_ + h)*4096;
  for (int i = tid; i < 4096; i += 256) cs[i>>6][i&63] = cg[i];
  for (int i = tid; i < 4096; i += 256) {
    int nn = i >> 6, dcol = i & 63;
    qs[nn][dcol] = qv[(size_t)(b*N_ + n0 + nn)*1024 + h*64 + dcol];
  }
  __syncthreads();
  int nn = tid >> 2, es = (tid & 3)*16;
  float o[16];
  #pragma unroll
  for (int j=0;j<16;++j) o[j]=0.f;
  for (int dcol = 0; dcol < 64; ++dcol) {
    float qd = qs[nn][dcol];
    #pragma unroll
    for (int j=0;j<16;++j) o[j] = fmaf(qd, cs[dcol][es+j], o[j]);
  }
  float* og = out_attn + (size_t)(b*N_ + n0 + nn)*512 + h*64 + es;
  #pragma unroll
  for (int j=0;j<16;++j) og[j] = o[j];
}

// ---------------- normalized prototypes: l2norm(K @ W_prot + b_prot) ----------------
__global__ __launch_bounds__(64) void protnorm_kernel(const float* __restrict__ K_spec, const float* __restrict__ K_spat,
                               const float* __restrict__ W_prot, const float* __restrict__ b_prot,
                               float* __restrict__ pnorm) {
  int row = blockIdx.x;          // route*128 + h*16 + m
  int route = row >> 7, hm = row & 127;
  const float* Km = (route ? K_spat : K_spec) + hm*64;
  int e = threadIdx.x;
  __shared__ float kv[64];
  kv[e] = Km[e];
  __syncthreads();
  float acc = b_prot[e];
  for (int dcol = 0; dcol < 64; ++dcol) acc = fmaf(kv[dcol], W_prot[dcol*64 + e], acc);
  float n2 = wave_reduce_sum(acc*acc);
  pnorm[(size_t)row*64 + e] = acc / fmaxf(sqrtf(n2), 1e-12f);
}

// ---------------- contrastive loss (per-token, wave per token) ----------------
__global__ __launch_bounds__(256) void contrastive_kernel(const float* __restrict__ qv,
                                   const float* __restrict__ r_spec, const float* __restrict__ r_spat,
                                   const float* __restrict__ W_tok, const float* __restrict__ b_tok,
                                   const float* __restrict__ pnorm, float* __restrict__ accums) {
  int blk = blockIdx.x;
  int nt = blk & 63, h = (blk >> 6) & 7, b = blk >> 9;
  int n0 = nt*64;
  int tid = threadIdx.x, lane = tid & 63, wv = tid >> 6;
  __shared__ float Wt[64][65];
  __shared__ float vsb[64][65];
  __shared__ float ps[2][16][65];
  __shared__ float btk[64];
  __shared__ float bred[2][4];
  for (int i = tid; i < 4096; i += 256) Wt[i>>6][i&63] = W_tok[i];
  for (int i = tid; i < 4096; i += 256) {
    int nn = i >> 6, e = i & 63;
    vsb[nn][e] = qv[(size_t)(b*N_ + n0 + nn)*1024 + 512 + h*64 + e];
  }
  for (int i = tid; i < 2048; i += 256) {
    int route = i >> 10, m = (i >> 6) & 15, e = i & 63;
    ps[route][m][e] = pnorm[(size_t)(route*128 + h*16 + m)*64 + e];
  }
  if (tid < 64) btk[tid] = b_tok[tid];
  __syncthreads();
  const float* rsg = r_spec + (((size_t)b*H_ + h)*N_ + n0)*16;
  const float* rtg = r_spat + (((size_t)b*H_ + h)*N_ + n0)*16;
  float lspec = 0.f, lspat = 0.f;
  for (int nn = wv; nn < 64; nn += 4) {
    float t = btk[lane];
    for (int dcol = 0; dcol < 64; ++dcol) t = fmaf(vsb[nn][dcol], Wt[dcol][lane], t);
    float n2 = wave_reduce_sum(t*t);
    float tn = t / fmaxf(sqrtf(n2), 1e-12f);
    float sims0[16], sims1[16];
    #pragma unroll
    for (int m=0;m<16;++m) sims0[m] = wave_reduce_sum(tn * ps[0][m][lane]);
    #pragma unroll
    for (int m=0;m<16;++m) sims1[m] = wave_reduce_sum(tn * ps[1][m][lane]);
    float pos0=0.f, pos1=0.f, mx0=-1e30f, mx1=-1e30f;
    #pragma unroll
    for (int m=0;m<16;++m) {
      pos0 += sims0[m]*rsg[nn*16+m];
      pos1 += sims1[m]*rtg[nn*16+m];
      mx0 = fmaxf(mx0, sims0[m]);
      mx1 = fmaxf(mx1, sims1[m]);
    }
    float z0=0.f, z1=0.f;
    #pragma unroll
    for (int m=0;m<16;++m) {
      z0 += expf((sims0[m]-mx0)/TAU_);
      z1 += expf((sims1[m]-mx1)/TAU_);
    }
    lspec += pos0/TAU_ - (mx0/TAU_ + logf(z0));
    lspat += pos1/TAU_ - (mx1/TAU_ + logf(z1));
  }
  if (lane == 0) { bred[0][wv]=lspec; bred[1][wv]=lspat; }
  __syncthreads();
  if (tid == 0) {
    atomicAdd(&accums[0], bred[0][0]+bred[0][1]+bred[0][2]+bred[0][3]);
    atomicAdd(&accums[1], bred[1][0]+bred[1][1]+bred[1][2]+bred[1][3]);
  }
}

// ---------------- diversity regularizer ----------------
__global__ __launch_bounds__(64) void diversity_kernel(const float* __restrict__ K_spec, const float* __restrict__ K_spat,
                                 float* __restrict__ accums) {
  int route = blockIdx.x >> 3, h = blockIdx.x & 7;
  const float* Km = (route ? K_spat : K_spec) + h*16*64;
  int e = threadIdx.x;
  float s = 0.f, selfsum = 0.f;
  for (int m = 0; m < 16; ++m) {
    float x = Km[m*64 + e];
    float n2 = wave_reduce_sum(x*x);
    float p = x / fmaxf(sqrtf(n2), 1e-6f);
    s += p; selfsum += p*p;
  }
  float off = wave_reduce_sum(s*s - selfsum);
  if (e == 0) atomicAdd(&accums[2+route], off);
}

__global__ void zero_accums(float* accums){ if (threadIdx.x < 8) accums[threadIdx.x] = 0.f; }

__global__ void finalize_kernel(const float* __restrict__ accums, float* __restrict__ tail) {
  float loss_spec = -(accums[0] / (float)(B_*H_*N_));
  float loss_spat = -(accums[1] / (float)(B_*H_*N_));
  float contrastive = 0.5f*(loss_spec + loss_spat);
  float denom = (float)(H_*M_*(M_-1)) + 1e-6f;
  float diversity = 0.01f * (accums[2]/denom + accums[3]/denom);
  tail[0] = contrastive;
  tail[1] = diversity;
}

extern "C" void kernel_launch(void* const* d_in, const int* in_sizes, int n_in,
                              void* d_out, int out_size, void* d_ws, size_t ws_size,
                              hipStream_t stream) {
  const float* x       = (const float*)d_in[0];
  const float* W_qkv   = (const float*)d_in[1];
  const float* W_proj  = (const float*)d_in[2];
  const float* b_proj  = (const float*)d_in[3];
  const float* W_rspec = (const float*)d_in[4];
  const float* b_rspec = (const float*)d_in[5];
  const float* W_rspat = (const float*)d_in[6];
  const float* b_rspat = (const float*)d_in[7];
  const float* K_spec  = (const float*)d_in[8];
  const float* K_spat  = (const float*)d_in[9];
  const float* W_tok   = (const float*)d_in[10];
  const float* b_tok   = (const float*)d_in[11];
  const float* W_prot  = (const float*)d_in[12];
  const float* b_prot  = (const float*)d_in[13];
  float* out = (float*)d_out;

  float* ws = (float*)d_ws;
  float* qv       = ws;                 // 33,554,432 floats: [q(512) | v(512)] per token
  float* logits   = ws + 33554432;      // 8,388,608
  float* r_spec   = ws + 41943040;      // 4,194,304
  float* r_spat   = ws + 46137344;      // 4,194,304
  float* out_attn = ws + 33554432;      // overlays logits+r (consumed by then)
  float* ctxb     = ws + 50331648;      // 262,144
  float* pnorm    = ws + 50593792;      // 16,384
  float* accums   = ws + 50610176;      // 8

  dim3 blk256(256);

  // 1. router logits (fp32, no bias yet)
  gemm_ff<<<dim3(512,2), blk256, 0, stream>>>(x, W_rspec, logits,       32768, 128, 512, 512, 128, 256);
  gemm_ff<<<dim3(512,2), blk256, 0, stream>>>(x, W_rspat, logits + 128, 32768, 128, 512, 512, 128, 256);
  // 2. top-k masked softmax -> r_spec/r_spat  (B,H,N,M)
  router_topk<<<2048, blk256, 0, stream>>>(logits, b_rspec, b_rspat, r_spec, r_spat);
  // 3. q and v (cols 0..511 and 1024..1535 of W_qkv; k is unused by the reference)
  gemm_ff<<<dim3(512,8), blk256, 0, stream>>>(x, W_qkv,        qv,       32768, 512, 512, 512, 1536, 1024);
  gemm_ff<<<dim3(512,8), blk256, 0, stream>>>(x, W_qkv + 1024, qv + 512, 32768, 512, 512, 512, 1536, 1024);
  // 4. softmax-over-n context per (b,h)
  context_kernel<<<64, blk256, 0, stream>>>(r_spec, r_spat, K_spec, K_spat, qv, ctxb);
  // 5. losses
  zero_accums<<<1, 64, 0, stream>>>(accums);
  protnorm_kernel<<<256, 64, 0, stream>>>(K_spec, K_spat, W_prot, b_prot, pnorm);
  contrastive_kernel<<<4096, blk256, 0, stream>>>(qv, r_spec, r_spat, W_tok, b_tok, pnorm, accums);
  diversity_kernel<<<16, 64, 0, stream>>>(K_spec, K_spat, accums);
  // 6. attention output (overlays r/logits region — safe: r consumed above)
  attn_out_kernel<<<4096, blk256, 0, stream>>>(qv, ctxb, out_attn);
  // 7. final projection + bias -> fp32 out
  gemm_ff_bias<<<dim3(512,8), blk256, 0, stream>>>(out_attn, W_proj, b_proj, out, 32768, 512, 512, 512, 512, 512);
  // 8. scalars
  finalize_kernel<<<1, 1, 0, stream>>>(accums, out + 16777216);
}

// Round 3
// 1599.815 us; speedup vs baseline: 2.3788x; 2.3788x over previous
//
#include <hip/hip_runtime.h>
#include <math.h>

#define B_ 8
#define N_ 4096
#define C_ 512
#define H_ 8
#define D_ 64
#define M_ 16
#define BN_TOK (B_*N_)
#define TAU_ 0.1f

typedef short s8v __attribute__((ext_vector_type(8)));
typedef float f4v __attribute__((ext_vector_type(4)));

__device__ __forceinline__ float wave_reduce_sum(float v){
  #pragma unroll
  for (int o = 32; o > 0; o >>= 1) v += __shfl_xor(v, o);
  return v;
}

__device__ __forceinline__ unsigned short f2b(float f){
  unsigned int u = __float_as_uint(f);
  u += 0x7fffu + ((u >> 16) & 1u);           // RNE
  return (unsigned short)(u >> 16);
}

__device__ __forceinline__ s8v pack8(const float* f){
  s8v r;
  #pragma unroll
  for (int e = 0; e < 8; ++e) r[e] = (short)f2b(f[e]);
  return r;
}

// ============ bf16-MFMA GEMM: C[M,N] = A_f32[M,K=512] * B_f32[512,N] (+bias) ============
// 128x128 tile, BK=32, 256 thr = 4 waves, each wave 64x64 (4x4 of 16x16x32 mfma).
// LDS layout (both operands k-contiguous, chunk = 8 bf16 = 16B, XOR-swizzled):
//   Asm[m][chunk] at m*32 + (chunk^(m&3))*8   ; Bsm[n][chunk] at n*32 + (chunk^(n&3))*8
__global__ __launch_bounds__(256) void gemm_mfma(const float* __restrict__ A, const float* __restrict__ Bw,
                          const float* __restrict__ bias, float* __restrict__ C,
                          int lda, int ldb, int ldc,
                          int skip_thresh, int skip_amt) {
  __shared__ __align__(16) unsigned short Asm[128*32];
  __shared__ __align__(16) unsigned short Bsm[128*32];
  const int tid = threadIdx.x;
  const int bm = blockIdx.x * 128;
  const int bn = blockIdx.y * 128;
  const int wcol0 = bn + (bn >= skip_thresh ? skip_amt : 0);  // weight-col base (skips k-block of W_qkv)

  const int lane = tid & 63, w = tid >> 6;
  const int w0 = (w >> 1) * 64, c0 = (w & 1) * 64;
  const int lm = lane & 15, lg = lane >> 4;
  const int xr = lg ^ (lm & 3);    // swizzled chunk for fragment reads (m&3 == lm&3)

  // A staging map: thread covers row mA, 16 consecutive k (chunks 2*halfA, 2*halfA+1)
  const int mA = tid >> 1, halfA = tid & 1;
  // B staging map: thread covers col colB, chunks {khB, khB+2}
  const int colB = tid & 127, khB = tid >> 7;

  f4v acc[4][4];
  #pragma unroll
  for (int i = 0; i < 4; ++i)
    #pragma unroll
    for (int j = 0; j < 4; ++j) acc[i][j] = (f4v){0.f,0.f,0.f,0.f};

  for (int k0 = 0; k0 < 512; k0 += 32) {
    // ---- global loads into regs ----
    const float4* ag = (const float4*)(A + (size_t)(bm + mA) * lda + k0 + 16 * halfA);
    float4 a0 = ag[0], a1 = ag[1], a2 = ag[2], a3 = ag[3];
    const float* bg = Bw + (size_t)(k0 + khB * 8) * ldb + wcol0 + colB;
    float fb[16];
    #pragma unroll
    for (int r = 0; r < 8; ++r) fb[r] = bg[(size_t)r * ldb];
    #pragma unroll
    for (int r = 0; r < 8; ++r) fb[8 + r] = bg[(size_t)(16 + r) * ldb];

    __syncthreads();   // previous iter's frag reads complete
    {
      float fa[16] = {a0.x,a0.y,a0.z,a0.w, a1.x,a1.y,a1.z,a1.w,
                      a2.x,a2.y,a2.z,a2.w, a3.x,a3.y,a3.z,a3.w};
      int c1 = 2 * halfA, c2 = 2 * halfA + 1;
      *(s8v*)&Asm[mA*32 + ((c1 ^ (mA & 3)) << 3)] = pack8(&fa[0]);
      *(s8v*)&Asm[mA*32 + ((c2 ^ (mA & 3)) << 3)] = pack8(&fa[8]);
      int d1 = khB, d2 = khB + 2;
      *(s8v*)&Bsm[colB*32 + ((d1 ^ (colB & 3)) << 3)] = pack8(&fb[0]);
      *(s8v*)&Bsm[colB*32 + ((d2 ^ (colB & 3)) << 3)] = pack8(&fb[8]);
    }
    __syncthreads();

    s8v af[4], bf_[4];
    #pragma unroll
    for (int i = 0; i < 4; ++i) af[i]  = *(const s8v*)&Asm[(w0 + 16*i + lm)*32 + (xr << 3)];
    #pragma unroll
    for (int j = 0; j < 4; ++j) bf_[j] = *(const s8v*)&Bsm[(c0 + 16*j + lm)*32 + (xr << 3)];
    #pragma unroll
    for (int i = 0; i < 4; ++i)
      #pragma unroll
      for (int j = 0; j < 4; ++j)
        acc[i][j] = __builtin_amdgcn_mfma_f32_16x16x32_bf16(af[i], bf_[j], acc[i][j], 0, 0, 0);
  }

  // ---- epilogue: C/D layout col=lane&15, row=(lane>>4)*4+reg ----
  #pragma unroll
  for (int j = 0; j < 4; ++j) {
    int cc = bn + c0 + 16*j + lm;
    float bj = bias ? bias[cc] : 0.f;
    #pragma unroll
    for (int i = 0; i < 4; ++i) {
      int row = bm + w0 + 16*i + lg*4;
      #pragma unroll
      for (int r = 0; r < 4; ++r)
        C[(size_t)(row + r) * ldc + cc] = acc[i][j][r] + bj;
    }
  }
}

// ---------------- router top-k + masked softmax ----------------
__global__ __launch_bounds__(256) void router_topk(const float* __restrict__ logits,
                            const float* __restrict__ b_rspec, const float* __restrict__ b_rspat,
                            float* __restrict__ r_spec, float* __restrict__ r_spat) {
  int t = blockIdx.x * blockDim.x + threadIdx.x;
  if (t >= BN_TOK * H_ * 2) return;
  int route = t & 1, h = (t >> 1) & 7, bn = t >> 4;
  int b = bn >> 12, n = bn & 4095;
  const float* lg = logits + (size_t)bn*256 + route*128 + h*16;
  const float* bias = (route ? b_rspat : b_rspec) + h*16;
  float v[16];
  #pragma unroll
  for (int m=0;m<16;++m) v[m] = lg[m] + bias[m];
  float m1=-1e30f, m2=-1e30f, m3=-1e30f;
  #pragma unroll
  for (int m=0;m<16;++m){
    float x=v[m];
    if (x>m1){m3=m2;m2=m1;m1=x;}
    else if (x>m2){m3=m2;m2=x;}
    else if (x>m3){m3=x;}
  }
  float S=0.f, Sm=0.f, e[16];
  #pragma unroll
  for (int m=0;m<16;++m){ e[m]=expf(v[m]-m1); S+=e[m]; if (v[m]>=m3) Sm+=e[m]; }
  float denom = fmaxf(Sm/S, 1e-6f);
  float inv = 1.f/(S*denom);
  float* r = (route ? r_spat : r_spec) + (((size_t)b*H_ + h)*N_ + n)*16;
  #pragma unroll
  for (int m=0;m<16;++m) r[m] = (v[m] >= m3) ? e[m]*inv : 0.f;
}

// ------- context partial: per (b,h,chunk of 256 tokens): partial Z[d], partial (P^T V)[d][e] -------
// No max-subtraction: r rows are convex weights -> |K_eff| <= max|K_spec|+max|K_spat| ~ 0.2.
__global__ __launch_bounds__(256) void context_partial(const float* __restrict__ r_spec, const float* __restrict__ r_spat,
                               const float* __restrict__ K_spec, const float* __restrict__ K_spat,
                               const float* __restrict__ qv, float* __restrict__ pctx, float* __restrict__ pZ) {
  const int chunk = blockIdx.x & 15, bh = blockIdx.x >> 4;
  const int b = bh >> 3, h = bh & 7;
  const int tid = threadIdx.x;
  __shared__ float Ks[16][64], Kt[16][64];
  __shared__ float rs[64][17], rt[64][17];
  __shared__ float pb[64][65];
  __shared__ float vs[64][65];
  __shared__ float red[256];
  for (int i = tid; i < 1024; i += 256) {
    Ks[i>>6][i&63] = K_spec[h*1024 + i];
    Kt[i>>6][i&63] = K_spat[h*1024 + i];
  }
  const float* rsg = r_spec + ((size_t)bh*N_ + chunk*256)*16;
  const float* rtg = r_spat + ((size_t)bh*N_ + chunk*256)*16;
  const float* vg  = qv + 512 + h*64;
  const int d = tid & 63, nl = tid >> 6;
  const int dd = tid >> 2, es = (tid & 3) * 16;
  float zacc = 0.f;
  float cacc[16];
  #pragma unroll
  for (int j=0;j<16;++j) cacc[j]=0.f;
  __syncthreads();
  for (int t0 = 0; t0 < 4; ++t0) {
    const int n0 = chunk*256 + t0*64;
    for (int i = tid; i < 1024; i += 256) {
      rs[i>>4][i&15] = rsg[t0*1024 + i];
      rt[i>>4][i&15] = rtg[t0*1024 + i];
    }
    for (int i = tid; i < 4096; i += 256) {
      int nn = i >> 6, e = i & 63;
      vs[nn][e] = vg[(size_t)(b*N_ + n0 + nn)*1024 + e];
    }
    __syncthreads();
    for (int nn = nl; nn < 64; nn += 4) {
      float acc = 0.f;
      #pragma unroll
      for (int m=0;m<16;++m) acc += rs[nn][m]*Ks[m][d] + rt[nn][m]*Kt[m][d];
      float p = expf(acc);
      pb[nn][d] = p;
      zacc += p;
    }
    __syncthreads();
    for (int nn = 0; nn < 64; ++nn) {
      float pv = pb[nn][dd];
      #pragma unroll
      for (int j=0;j<16;++j) cacc[j] = fmaf(pv, vs[nn][es+j], cacc[j]);
    }
    __syncthreads();
  }
  red[tid] = zacc; __syncthreads();
  if (tid < 64) pZ[(size_t)(bh*16 + chunk)*64 + tid] = red[tid]+red[tid+64]+red[tid+128]+red[tid+192];
  float* pc = pctx + ((size_t)(bh*16 + chunk)*64 + dd)*64 + es;
  #pragma unroll
  for (int j=0;j<16;++j) pc[j] = cacc[j];
}

__global__ __launch_bounds__(256) void context_reduce(const float* __restrict__ pctx, const float* __restrict__ pZ,
                              float* __restrict__ ctx) {
  const int bh = blockIdx.x;
  const int tid = threadIdx.x;
  const int dd = tid >> 2, es = (tid & 3) * 16;
  float z = 0.f;
  for (int c = 0; c < 16; ++c) z += pZ[(size_t)(bh*16 + c)*64 + dd];
  float s[16];
  #pragma unroll
  for (int j=0;j<16;++j) s[j]=0.f;
  for (int c = 0; c < 16; ++c) {
    const float* pc = pctx + ((size_t)(bh*16 + c)*64 + dd)*64 + es;
    #pragma unroll
    for (int j=0;j<16;++j) s[j] += pc[j];
  }
  float inv = 1.f / z;
  float* co = ctx + ((size_t)bh*64 + dd)*64 + es;
  #pragma unroll
  for (int j=0;j<16;++j) co[j] = s[j]*inv;
}

// ---------------- out_attn[b,n,h*64+e] = q[b,n,h,:] @ context[b,h] ----------------
__global__ __launch_bounds__(256) void attn_out_kernel(const float* __restrict__ qv, const float* __restrict__ ctx,
                                float* __restrict__ out_attn) {
  int blk = blockIdx.x;
  int nt = blk & 63, h = (blk >> 6) & 7, b = blk >> 9;
  int n0 = nt * 64;
  __shared__ float cs[64][65];
  __shared__ float qs[64][65];
  int tid = threadIdx.x;
  const float* cg = ctx + ((size_t)b*H_ + h)*4096;
  for (int i = tid; i < 4096; i += 256) cs[i>>6][i&63] = cg[i];
  for (int i = tid; i < 4096; i += 256) {
    int nn = i >> 6, dcol = i & 63;
    qs[nn][dcol] = qv[(size_t)(b*N_ + n0 + nn)*1024 + h*64 + dcol];
  }
  __syncthreads();
  int nn = tid >> 2, es = (tid & 3)*16;
  float o[16];
  #pragma unroll
  for (int j=0;j<16;++j) o[j]=0.f;
  for (int dcol = 0; dcol < 64; ++dcol) {
    float qd = qs[nn][dcol];
    #pragma unroll
    for (int j=0;j<16;++j) o[j] = fmaf(qd, cs[dcol][es+j], o[j]);
  }
  float* og = out_attn + (size_t)(b*N_ + n0 + nn)*512 + h*64 + es;
  #pragma unroll
  for (int j=0;j<16;++j) og[j] = o[j];
}

// ---------------- normalized prototypes: l2norm(K @ W_prot + b_prot) ----------------
__global__ __launch_bounds__(64) void protnorm_kernel(const float* __restrict__ K_spec, const float* __restrict__ K_spat,
                               const float* __restrict__ W_prot, const float* __restrict__ b_prot,
                               float* __restrict__ pnorm) {
  int row = blockIdx.x;          // route*128 + h*16 + m
  int route = row >> 7, hm = row & 127;
  const float* Km = (route ? K_spat : K_spec) + hm*64;
  int e = threadIdx.x;
  __shared__ float kv[64];
  kv[e] = Km[e];
  __syncthreads();
  float acc = b_prot[e];
  for (int dcol = 0; dcol < 64; ++dcol) acc = fmaf(kv[dcol], W_prot[dcol*64 + e], acc);
  float n2 = wave_reduce_sum(acc*acc);
  pnorm[(size_t)row*64 + e] = acc / fmaxf(sqrtf(n2), 1e-12f);
}

// ---------------- contrastive loss (per-token, wave per token) ----------------
__global__ __launch_bounds__(256) void contrastive_kernel(const float* __restrict__ qv,
                                   const float* __restrict__ r_spec, const float* __restrict__ r_spat,
                                   const float* __restrict__ W_tok, const float* __restrict__ b_tok,
                                   const float* __restrict__ pnorm, float* __restrict__ accums) {
  int blk = blockIdx.x;
  int nt = blk & 63, h = (blk >> 6) & 7, b = blk >> 9;
  int n0 = nt*64;
  int tid = threadIdx.x, lane = tid & 63, wv = tid >> 6;
  __shared__ float Wt[64][65];
  __shared__ float vsb[64][65];
  __shared__ float ps[2][16][65];
  __shared__ float btk[64];
  __shared__ float bred[2][4];
  for (int i = tid; i < 4096; i += 256) Wt[i>>6][i&63] = W_tok[i];
  for (int i = tid; i < 4096; i += 256) {
    int nn = i >> 6, e = i & 63;
    vsb[nn][e] = qv[(size_t)(b*N_ + n0 + nn)*1024 + 512 + h*64 + e];
  }
  for (int i = tid; i < 2048; i += 256) {
    int route = i >> 10, m = (i >> 6) & 15, e = i & 63;
    ps[route][m][e] = pnorm[(size_t)(route*128 + h*16 + m)*64 + e];
  }
  if (tid < 64) btk[tid] = b_tok[tid];
  __syncthreads();
  const float* rsg = r_spec + (((size_t)b*H_ + h)*N_ + n0)*16;
  const float* rtg = r_spat + (((size_t)b*H_ + h)*N_ + n0)*16;
  float lspec = 0.f, lspat = 0.f;
  for (int nn = wv; nn < 64; nn += 4) {
    float t = btk[lane];
    for (int dcol = 0; dcol < 64; ++dcol) t = fmaf(vsb[nn][dcol], Wt[dcol][lane], t);
    float n2 = wave_reduce_sum(t*t);
    float tn = t / fmaxf(sqrtf(n2), 1e-12f);
    float sims0[16], sims1[16];
    #pragma unroll
    for (int m=0;m<16;++m) sims0[m] = wave_reduce_sum(tn * ps[0][m][lane]);
    #pragma unroll
    for (int m=0;m<16;++m) sims1[m] = wave_reduce_sum(tn * ps[1][m][lane]);
    float pos0=0.f, pos1=0.f, mx0=-1e30f, mx1=-1e30f;
    #pragma unroll
    for (int m=0;m<16;++m) {
      pos0 += sims0[m]*rsg[nn*16+m];
      pos1 += sims1[m]*rtg[nn*16+m];
      mx0 = fmaxf(mx0, sims0[m]);
      mx1 = fmaxf(mx1, sims1[m]);
    }
    float z0=0.f, z1=0.f;
    #pragma unroll
    for (int m=0;m<16;++m) {
      z0 += expf((sims0[m]-mx0)/TAU_);
      z1 += expf((sims1[m]-mx1)/TAU_);
    }
    lspec += pos0/TAU_ - (mx0/TAU_ + logf(z0));
    lspat += pos1/TAU_ - (mx1/TAU_ + logf(z1));
  }
  if (lane == 0) { bred[0][wv]=lspec; bred[1][wv]=lspat; }
  __syncthreads();
  if (tid == 0) {
    atomicAdd(&accums[0], bred[0][0]+bred[0][1]+bred[0][2]+bred[0][3]);
    atomicAdd(&accums[1], bred[1][0]+bred[1][1]+bred[1][2]+bred[1][3]);
  }
}

// ---------------- diversity regularizer ----------------
__global__ __launch_bounds__(64) void diversity_kernel(const float* __restrict__ K_spec, const float* __restrict__ K_spat,
                                 float* __restrict__ accums) {
  int route = blockIdx.x >> 3, h = blockIdx.x & 7;
  const float* Km = (route ? K_spat : K_spec) + h*16*64;
  int e = threadIdx.x;
  float s = 0.f, selfsum = 0.f;
  for (int m = 0; m < 16; ++m) {
    float x = Km[m*64 + e];
    float n2 = wave_reduce_sum(x*x);
    float p = x / fmaxf(sqrtf(n2), 1e-6f);
    s += p; selfsum += p*p;
  }
  float off = wave_reduce_sum(s*s - selfsum);
  if (e == 0) atomicAdd(&accums[2+route], off);
}

__global__ void zero_accums(float* accums){ if (threadIdx.x < 8) accums[threadIdx.x] = 0.f; }

__global__ void finalize_kernel(const float* __restrict__ accums, float* __restrict__ tail) {
  float loss_spec = -(accums[0] / (float)(B_*H_*N_));
  float loss_spat = -(accums[1] / (float)(B_*H_*N_));
  float contrastive = 0.5f*(loss_spec + loss_spat);
  float denom = (float)(H_*M_*(M_-1)) + 1e-6f;
  float diversity = 0.01f * (accums[2]/denom + accums[3]/denom);
  tail[0] = contrastive;
  tail[1] = diversity;
}

extern "C" void kernel_launch(void* const* d_in, const int* in_sizes, int n_in,
                              void* d_out, int out_size, void* d_ws, size_t ws_size,
                              hipStream_t stream) {
  const float* x       = (const float*)d_in[0];
  const float* W_qkv   = (const float*)d_in[1];
  const float* W_proj  = (const float*)d_in[2];
  const float* b_proj  = (const float*)d_in[3];
  const float* W_rspec = (const float*)d_in[4];
  const float* b_rspec = (const float*)d_in[5];
  const float* W_rspat = (const float*)d_in[6];
  const float* b_rspat = (const float*)d_in[7];
  const float* K_spec  = (const float*)d_in[8];
  const float* K_spat  = (const float*)d_in[9];
  const float* W_tok   = (const float*)d_in[10];
  const float* b_tok   = (const float*)d_in[11];
  const float* W_prot  = (const float*)d_in[12];
  const float* b_prot  = (const float*)d_in[13];
  float* out = (float*)d_out;

  float* ws = (float*)d_ws;
  float* qv       = ws;                 // 33,554,432 floats: [q(512) | v(512)] per token
  float* logits   = ws + 33554432;      // 8,388,608 (freed after router_topk)
  float* pctx     = ws + 33554432;      // 4,194,304  (overlays logits)
  float* pZ       = ws + 37748736;      // 65,536     (overlays logits)
  float* r_spec   = ws + 41943040;      // 4,194,304
  float* r_spat   = ws + 46137344;      // 4,194,304
  float* out_attn = ws + 33554432;      // 16,777,216 (overlays logits+r; written after they're consumed)
  float* ctxb     = ws + 50331648;      // 262,144
  float* pnorm    = ws + 50593792;      // 16,384
  float* accums   = ws + 50610176;      // 8

  dim3 blk256(256);

  // 1. router logits via MFMA (bias added in topk)
  gemm_mfma<<<dim3(256,1), blk256, 0, stream>>>(x, W_rspec, nullptr, logits,       512, 128, 256, 1<<30, 0);
  gemm_mfma<<<dim3(256,1), blk256, 0, stream>>>(x, W_rspat, nullptr, logits + 128, 512, 128, 256, 1<<30, 0);
  // 2. top-k masked softmax -> r_spec/r_spat  (B,H,N,M)
  router_topk<<<2048, blk256, 0, stream>>>(logits, b_rspec, b_rspat, r_spec, r_spat);
  // 3. fused q+v GEMM: output cols 0..511 = q (W cols 0..511), 512..1023 = v (W cols 1024..1535)
  gemm_mfma<<<dim3(256,8), blk256, 0, stream>>>(x, W_qkv, nullptr, qv, 512, 1536, 1024, 512, 512);
  // 4. softmax-over-n context: partials then reduce
  context_partial<<<1024, blk256, 0, stream>>>(r_spec, r_spat, K_spec, K_spat, qv, pctx, pZ);
  context_reduce<<<64, blk256, 0, stream>>>(pctx, pZ, ctxb);
  // 5. losses
  zero_accums<<<1, 64, 0, stream>>>(accums);
  protnorm_kernel<<<256, 64, 0, stream>>>(K_spec, K_spat, W_prot, b_prot, pnorm);
  contrastive_kernel<<<4096, blk256, 0, stream>>>(qv, r_spec, r_spat, W_tok, b_tok, pnorm, accums);
  diversity_kernel<<<16, 64, 0, stream>>>(K_spec, K_spat, accums);
  // 6. attention output (overlays pctx/logits region — consumed above)
  attn_out_kernel<<<4096, blk256, 0, stream>>>(qv, ctxb, out_attn);
  // 7. final projection + bias -> fp32 out
  gemm_mfma<<<dim3(256,4), blk256, 0, stream>>>(out_attn, W_proj, b_proj, out, 512, 512, 512, 1<<30, 0);
  // 8. scalars
  finalize_kernel<<<1, 1, 0, stream>>>(accums, out + 16777216);
}

// Round 4
// 726.817 us; speedup vs baseline: 5.2361x; 2.2011x over previous
//
#include <hip/hip_runtime.h>
#include <math.h>

#define B_ 8
#define N_ 4096
#define C_ 512
#define H_ 8
#define D_ 64
#define M_ 16
#define BN_TOK (B_*N_)
#define TAU_ 0.1f

typedef short s8v __attribute__((ext_vector_type(8)));
typedef float f4v __attribute__((ext_vector_type(4)));

__device__ __forceinline__ float wave_reduce_sum(float v){
  #pragma unroll
  for (int o = 32; o > 0; o >>= 1) v += __shfl_xor(v, o);
  return v;
}

__device__ __forceinline__ unsigned short f2b(float f){
  unsigned int u = __float_as_uint(f);
  u += 0x7fffu + ((u >> 16) & 1u);           // RNE
  return (unsigned short)(u >> 16);
}

__device__ __forceinline__ s8v pack8(const float* f){
  s8v r;
  #pragma unroll
  for (int e = 0; e < 8; ++e) r[e] = (short)f2b(f[e]);
  return r;
}

// ============ bf16-MFMA GEMM: C[M,N] = A_f32[M,K=512] * B_f32[512,N] (+bias) ============
__global__ __launch_bounds__(256) void gemm_mfma(const float* __restrict__ A, const float* __restrict__ Bw,
                          const float* __restrict__ bias, float* __restrict__ C,
                          int lda, int ldb, int ldc,
                          int skip_thresh, int skip_amt) {
  __shared__ __align__(16) unsigned short Asm[128*32];
  __shared__ __align__(16) unsigned short Bsm[128*32];
  const int tid = threadIdx.x;
  const int bm = blockIdx.x * 128;
  const int bn = blockIdx.y * 128;
  const int wcol0 = bn + (bn >= skip_thresh ? skip_amt : 0);

  const int lane = tid & 63, w = tid >> 6;
  const int w0 = (w >> 1) * 64, c0 = (w & 1) * 64;
  const int lm = lane & 15, lg = lane >> 4;
  const int xr = lg ^ (lm & 3);

  const int mA = tid >> 1, halfA = tid & 1;
  const int colB = tid & 127, khB = tid >> 7;

  f4v acc[4][4];
  #pragma unroll
  for (int i = 0; i < 4; ++i)
    #pragma unroll
    for (int j = 0; j < 4; ++j) acc[i][j] = (f4v){0.f,0.f,0.f,0.f};

  for (int k0 = 0; k0 < 512; k0 += 32) {
    const float4* ag = (const float4*)(A + (size_t)(bm + mA) * lda + k0 + 16 * halfA);
    float4 a0 = ag[0], a1 = ag[1], a2 = ag[2], a3 = ag[3];
    const float* bg = Bw + (size_t)(k0 + khB * 8) * ldb + wcol0 + colB;
    float fb[16];
    #pragma unroll
    for (int r = 0; r < 8; ++r) fb[r] = bg[(size_t)r * ldb];
    #pragma unroll
    for (int r = 0; r < 8; ++r) fb[8 + r] = bg[(size_t)(16 + r) * ldb];

    __syncthreads();
    {
      float fa[16] = {a0.x,a0.y,a0.z,a0.w, a1.x,a1.y,a1.z,a1.w,
                      a2.x,a2.y,a2.z,a2.w, a3.x,a3.y,a3.z,a3.w};
      int c1 = 2 * halfA, c2 = 2 * halfA + 1;
      *(s8v*)&Asm[mA*32 + ((c1 ^ (mA & 3)) << 3)] = pack8(&fa[0]);
      *(s8v*)&Asm[mA*32 + ((c2 ^ (mA & 3)) << 3)] = pack8(&fa[8]);
      int d1 = khB, d2 = khB + 2;
      *(s8v*)&Bsm[colB*32 + ((d1 ^ (colB & 3)) << 3)] = pack8(&fb[0]);
      *(s8v*)&Bsm[colB*32 + ((d2 ^ (colB & 3)) << 3)] = pack8(&fb[8]);
    }
    __syncthreads();

    s8v af[4], bf_[4];
    #pragma unroll
    for (int i = 0; i < 4; ++i) af[i]  = *(const s8v*)&Asm[(w0 + 16*i + lm)*32 + (xr << 3)];
    #pragma unroll
    for (int j = 0; j < 4; ++j) bf_[j] = *(const s8v*)&Bsm[(c0 + 16*j + lm)*32 + (xr << 3)];
    #pragma unroll
    for (int i = 0; i < 4; ++i)
      #pragma unroll
      for (int j = 0; j < 4; ++j)
        acc[i][j] = __builtin_amdgcn_mfma_f32_16x16x32_bf16(af[i], bf_[j], acc[i][j], 0, 0, 0);
  }

  #pragma unroll
  for (int j = 0; j < 4; ++j) {
    int cc = bn + c0 + 16*j + lm;
    float bj = bias ? bias[cc] : 0.f;
    #pragma unroll
    for (int i = 0; i < 4; ++i) {
      int row = bm + w0 + 16*i + lg*4;
      #pragma unroll
      for (int r = 0; r < 4; ++r)
        C[(size_t)(row + r) * ldc + cc] = acc[i][j][r] + bj;
    }
  }
}

// ---------------- router top-k + masked softmax ----------------
__global__ __launch_bounds__(256) void router_topk(const float* __restrict__ logits,
                            const float* __restrict__ b_rspec, const float* __restrict__ b_rspat,
                            float* __restrict__ r_spec, float* __restrict__ r_spat) {
  int t = blockIdx.x * blockDim.x + threadIdx.x;
  if (t >= BN_TOK * H_ * 2) return;
  int route = t & 1, h = (t >> 1) & 7, bn = t >> 4;
  int b = bn >> 12, n = bn & 4095;
  const float* lg = logits + (size_t)bn*256 + route*128 + h*16;
  const float* bias = (route ? b_rspat : b_rspec) + h*16;
  float v[16];
  #pragma unroll
  for (int m=0;m<16;++m) v[m] = lg[m] + bias[m];
  float m1=-1e30f, m2=-1e30f, m3=-1e30f;
  #pragma unroll
  for (int m=0;m<16;++m){
    float x=v[m];
    if (x>m1){m3=m2;m2=m1;m1=x;}
    else if (x>m2){m3=m2;m2=x;}
    else if (x>m3){m3=x;}
  }
  float S=0.f, Sm=0.f, e[16];
  #pragma unroll
  for (int m=0;m<16;++m){ e[m]=expf(v[m]-m1); S+=e[m]; if (v[m]>=m3) Sm+=e[m]; }
  float denom = fmaxf(Sm/S, 1e-6f);
  float inv = 1.f/(S*denom);
  float* r = (route ? r_spat : r_spec) + (((size_t)b*H_ + h)*N_ + n)*16;
  #pragma unroll
  for (int m=0;m<16;++m) r[m] = (v[m] >= m3) ? e[m]*inv : 0.f;
}

// ------- context partial: per (b,h,chunk of 256 tokens) -------
__global__ __launch_bounds__(256) void context_partial(const float* __restrict__ r_spec, const float* __restrict__ r_spat,
                               const float* __restrict__ K_spec, const float* __restrict__ K_spat,
                               const float* __restrict__ qv, float* __restrict__ pctx, float* __restrict__ pZ) {
  const int chunk = blockIdx.x & 15, bh = blockIdx.x >> 4;
  const int b = bh >> 3, h = bh & 7;
  const int tid = threadIdx.x;
  __shared__ float Ks[16][64], Kt[16][64];
  __shared__ float rs[64][17], rt[64][17];
  __shared__ float pb[64][65];
  __shared__ float vs[64][65];
  __shared__ float red[256];
  for (int i = tid; i < 1024; i += 256) {
    Ks[i>>6][i&63] = K_spec[h*1024 + i];
    Kt[i>>6][i&63] = K_spat[h*1024 + i];
  }
  const float* rsg = r_spec + ((size_t)bh*N_ + chunk*256)*16;
  const float* rtg = r_spat + ((size_t)bh*N_ + chunk*256)*16;
  const float* vg  = qv + 512 + h*64;
  const int d = tid & 63, nl = tid >> 6;
  const int dd = tid >> 2, es = (tid & 3) * 16;
  float zacc = 0.f;
  float cacc[16];
  #pragma unroll
  for (int j=0;j<16;++j) cacc[j]=0.f;
  __syncthreads();
  for (int t0 = 0; t0 < 4; ++t0) {
    const int n0 = chunk*256 + t0*64;
    for (int i = tid; i < 1024; i += 256) {
      rs[i>>4][i&15] = rsg[t0*1024 + i];
      rt[i>>4][i&15] = rtg[t0*1024 + i];
    }
    for (int i = tid; i < 4096; i += 256) {
      int nn = i >> 6, e = i & 63;
      vs[nn][e] = vg[(size_t)(b*N_ + n0 + nn)*1024 + e];
    }
    __syncthreads();
    for (int nn = nl; nn < 64; nn += 4) {
      float acc = 0.f;
      #pragma unroll
      for (int m=0;m<16;++m) acc += rs[nn][m]*Ks[m][d] + rt[nn][m]*Kt[m][d];
      float p = expf(acc);
      pb[nn][d] = p;
      zacc += p;
    }
    __syncthreads();
    for (int nn = 0; nn < 64; ++nn) {
      float pv = pb[nn][dd];
      #pragma unroll
      for (int j=0;j<16;++j) cacc[j] = fmaf(pv, vs[nn][es+j], cacc[j]);
    }
    __syncthreads();
  }
  red[tid] = zacc; __syncthreads();
  if (tid < 64) pZ[(size_t)(bh*16 + chunk)*64 + tid] = red[tid]+red[tid+64]+red[tid+128]+red[tid+192];
  float* pc = pctx + ((size_t)(bh*16 + chunk)*64 + dd)*64 + es;
  #pragma unroll
  for (int j=0;j<16;++j) pc[j] = cacc[j];
}

__global__ __launch_bounds__(256) void context_reduce(const float* __restrict__ pctx, const float* __restrict__ pZ,
                              float* __restrict__ ctx) {
  const int bh = blockIdx.x;
  const int tid = threadIdx.x;
  const int dd = tid >> 2, es = (tid & 3) * 16;
  float z = 0.f;
  for (int c = 0; c < 16; ++c) z += pZ[(size_t)(bh*16 + c)*64 + dd];
  float s[16];
  #pragma unroll
  for (int j=0;j<16;++j) s[j]=0.f;
  for (int c = 0; c < 16; ++c) {
    const float* pc = pctx + ((size_t)(bh*16 + c)*64 + dd)*64 + es;
    #pragma unroll
    for (int j=0;j<16;++j) s[j] += pc[j];
  }
  float inv = 1.f / z;
  float* co = ctx + ((size_t)bh*64 + dd)*64 + es;
  #pragma unroll
  for (int j=0;j<16;++j) co[j] = s[j]*inv;
}

// ---------------- out_attn ----------------
__global__ __launch_bounds__(256) void attn_out_kernel(const float* __restrict__ qv, const float* __restrict__ ctx,
                                float* __restrict__ out_attn) {
  int blk = blockIdx.x;
  int nt = blk & 63, h = (blk >> 6) & 7, b = blk >> 9;
  int n0 = nt * 64;
  __shared__ float cs[64][65];
  __shared__ float qs[64][65];
  int tid = threadIdx.x;
  const float* cg = ctx + ((size_t)b*H_ + h)*4096;
  for (int i = tid; i < 4096; i += 256) cs[i>>6][i&63] = cg[i];
  for (int i = tid; i < 4096; i += 256) {
    int nn = i >> 6, dcol = i & 63;
    qs[nn][dcol] = qv[(size_t)(b*N_ + n0 + nn)*1024 + h*64 + dcol];
  }
  __syncthreads();
  int nn = tid >> 2, es = (tid & 3)*16;
  float o[16];
  #pragma unroll
  for (int j=0;j<16;++j) o[j]=0.f;
  for (int dcol = 0; dcol < 64; ++dcol) {
    float qd = qs[nn][dcol];
    #pragma unroll
    for (int j=0;j<16;++j) o[j] = fmaf(qd, cs[dcol][es+j], o[j]);
  }
  float* og = out_attn + (size_t)(b*N_ + n0 + nn)*512 + h*64 + es;
  #pragma unroll
  for (int j=0;j<16;++j) og[j] = o[j];
}

// ---------------- normalized prototypes ----------------
__global__ __launch_bounds__(64) void protnorm_kernel(const float* __restrict__ K_spec, const float* __restrict__ K_spat,
                               const float* __restrict__ W_prot, const float* __restrict__ b_prot,
                               float* __restrict__ pnorm) {
  int row = blockIdx.x;
  int route = row >> 7, hm = row & 127;
  const float* Km = (route ? K_spat : K_spec) + hm*64;
  int e = threadIdx.x;
  __shared__ float kv[64];
  kv[e] = Km[e];
  __syncthreads();
  float acc = b_prot[e];
  for (int dcol = 0; dcol < 64; ++dcol) acc = fmaf(kv[dcol], W_prot[dcol*64 + e], acc);
  float n2 = wave_reduce_sum(acc*acc);
  pnorm[(size_t)row*64 + e] = acc / fmaxf(sqrtf(n2), 1e-12f);
}

// ---------------- contrastive loss via MFMA ----------------
// per block: head h, 128 tokens. T = V@W_tok + b_tok (MFMA), S = T@P^T (MFMA),
// sims = S / max(||t||,1e-12); loss epilogue scalar.
__global__ __launch_bounds__(256) void contrastive_mfma(const float* __restrict__ qv,
                                   const float* __restrict__ r_spec, const float* __restrict__ r_spat,
                                   const float* __restrict__ W_tok, const float* __restrict__ b_tok,
                                   const float* __restrict__ pnorm, float* __restrict__ accums) {
  const int tile = blockIdx.x & 255;     // 256 tiles x 128 tokens = 32768
  const int h = blockIdx.x >> 8;
  const int t0 = tile * 128;
  const int b = t0 >> 12;
  const int n0 = t0 & 4095;
  const int tid = threadIdx.x;
  const int lane = tid & 63, w = tid >> 6;
  const int lm = lane & 15, lg = lane >> 4;

  __shared__ __align__(16) unsigned short Vsm[128*72];
  __shared__ __align__(16) unsigned short Wsm[64*72];
  __shared__ __align__(16) unsigned short Psm[32*72];
  __shared__ __align__(16) unsigned short Tsm[128*72];
  __shared__ float Ssm[128*36];
  __shared__ float nrmS[128];
  __shared__ float btkS[64];
  __shared__ float bred[2][4];

  // stage V tile (rows = tokens, 64 e) as bf16
  {
    const int vr = tid >> 1, vh = tid & 1;
    const float* vg = qv + (size_t)(b*N_ + n0 + vr)*1024 + 512 + h*64 + vh*32;
    float f[32];
    #pragma unroll
    for (int i = 0; i < 8; ++i) {
      float4 v4 = ((const float4*)vg)[i];
      f[4*i]=v4.x; f[4*i+1]=v4.y; f[4*i+2]=v4.z; f[4*i+3]=v4.w;
    }
    #pragma unroll
    for (int c = 0; c < 4; ++c) *(s8v*)&Vsm[vr*72 + vh*32 + c*8] = pack8(&f[8*c]);
  }
  // stage W_tok transposed: Wsm[e][d-contiguous]
  {
    const int e = tid & 63, kh = tid >> 6;
    float f[16];
    #pragma unroll
    for (int rr = 0; rr < 16; ++rr) f[rr] = W_tok[(size_t)(kh*16+rr)*64 + e];
    *(s8v*)&Wsm[e*72 + kh*16]     = pack8(&f[0]);
    *(s8v*)&Wsm[e*72 + kh*16 + 8] = pack8(&f[8]);
  }
  // stage P (32 protos: 16 spec, 16 spat) rows e-contiguous
  if (tid < 128) {
    const int proto = tid >> 2, q4 = tid & 3;
    const int src = (proto < 16) ? (h*16 + proto) : (128 + h*16 + (proto-16));
    const float* pg = pnorm + (size_t)src*64 + q4*16;
    float f[16];
    #pragma unroll
    for (int i = 0; i < 4; ++i) {
      float4 v4 = ((const float4*)pg)[i];
      f[4*i]=v4.x; f[4*i+1]=v4.y; f[4*i+2]=v4.z; f[4*i+3]=v4.w;
    }
    *(s8v*)&Psm[proto*72 + q4*16]     = pack8(&f[0]);
    *(s8v*)&Psm[proto*72 + q4*16 + 8] = pack8(&f[8]);
  }
  if (tid < 64) btkS[tid] = b_tok[tid];
  __syncthreads();

  // 1st MFMA: T[128x64] = V @ Wsm^T-layout (A rows = tokens, B cols = e)
  f4v acc[2][4];
  #pragma unroll
  for (int i=0;i<2;++i)
    #pragma unroll
    for (int j=0;j<4;++j) acc[i][j] = (f4v){0.f,0.f,0.f,0.f};
  {
    s8v bf0[4], bf1[4];
    #pragma unroll
    for (int j=0;j<4;++j) {
      bf0[j] = *(const s8v*)&Wsm[(j*16+lm)*72 + lg*8];
      bf1[j] = *(const s8v*)&Wsm[(j*16+lm)*72 + 32 + lg*8];
    }
    #pragma unroll
    for (int i=0;i<2;++i) {
      s8v af0 = *(const s8v*)&Vsm[(w*32+16*i+lm)*72 + lg*8];
      s8v af1 = *(const s8v*)&Vsm[(w*32+16*i+lm)*72 + 32 + lg*8];
      #pragma unroll
      for (int j=0;j<4;++j) {
        acc[i][j] = __builtin_amdgcn_mfma_f32_16x16x32_bf16(af0, bf0[j], acc[i][j], 0, 0, 0);
        acc[i][j] = __builtin_amdgcn_mfma_f32_16x16x32_bf16(af1, bf1[j], acc[i][j], 0, 0, 0);
      }
    }
  }
  // bias, row norms (butterfly over lm), write T bf16
  #pragma unroll
  for (int i=0;i<2;++i) {
    #pragma unroll
    for (int r=0;r<4;++r) {
      float s = 0.f;
      #pragma unroll
      for (int j=0;j<4;++j) {
        float val = acc[i][j][r] + btkS[j*16+lm];
        acc[i][j][r] = val;
        s += val*val;
      }
      s += __shfl_xor(s,1); s += __shfl_xor(s,2); s += __shfl_xor(s,4); s += __shfl_xor(s,8);
      if (lm == 0) nrmS[w*32 + 16*i + lg*4 + r] = s;
    }
  }
  #pragma unroll
  for (int i=0;i<2;++i)
    #pragma unroll
    for (int j=0;j<4;++j)
      #pragma unroll
      for (int r=0;r<4;++r)
        Tsm[(w*32+16*i+lg*4+r)*72 + j*16+lm] = f2b(acc[i][j][r]);
  __syncthreads();

  // 2nd MFMA: S[128x32] = T @ P^T
  f4v acc2[2][2];
  #pragma unroll
  for (int i=0;i<2;++i)
    #pragma unroll
    for (int j=0;j<2;++j) acc2[i][j] = (f4v){0.f,0.f,0.f,0.f};
  {
    s8v bf0[2], bf1[2];
    #pragma unroll
    for (int j=0;j<2;++j) {
      bf0[j] = *(const s8v*)&Psm[(j*16+lm)*72 + lg*8];
      bf1[j] = *(const s8v*)&Psm[(j*16+lm)*72 + 32 + lg*8];
    }
    #pragma unroll
    for (int i=0;i<2;++i) {
      s8v af0 = *(const s8v*)&Tsm[(w*32+16*i+lm)*72 + lg*8];
      s8v af1 = *(const s8v*)&Tsm[(w*32+16*i+lm)*72 + 32 + lg*8];
      #pragma unroll
      for (int j=0;j<2;++j) {
        acc2[i][j] = __builtin_amdgcn_mfma_f32_16x16x32_bf16(af0, bf0[j], acc2[i][j], 0, 0, 0);
        acc2[i][j] = __builtin_amdgcn_mfma_f32_16x16x32_bf16(af1, bf1[j], acc2[i][j], 0, 0, 0);
      }
    }
  }
  #pragma unroll
  for (int i=0;i<2;++i)
    #pragma unroll
    for (int j=0;j<2;++j)
      #pragma unroll
      for (int r=0;r<4;++r)
        Ssm[(w*32+16*i+lg*4+r)*36 + j*16+lm] = acc2[i][j][r];
  __syncthreads();

  // loss epilogue: one thread per token
  float lspec = 0.f, lspat = 0.f;
  if (tid < 128) {
    const int tt = tid;
    float inv = 1.f / fmaxf(sqrtf(nrmS[tt]), 1e-12f);
    const float* rsg = r_spec + (((size_t)b*H_ + h)*N_ + n0 + tt)*16;
    const float* rtg = r_spat + (((size_t)b*H_ + h)*N_ + n0 + tt)*16;
    float s0[16], s1[16];
    #pragma unroll
    for (int m=0;m<16;++m) { s0[m] = Ssm[tt*36 + m]*inv; s1[m] = Ssm[tt*36 + 16 + m]*inv; }
    float pos0=0.f, pos1=0.f, mx0=-1e30f, mx1=-1e30f;
    #pragma unroll
    for (int m=0;m<16;++m) {
      pos0 += s0[m]*rsg[m];
      pos1 += s1[m]*rtg[m];
      mx0 = fmaxf(mx0, s0[m]);
      mx1 = fmaxf(mx1, s1[m]);
    }
    float z0=0.f, z1=0.f;
    #pragma unroll
    for (int m=0;m<16;++m) {
      z0 += expf((s0[m]-mx0)/TAU_);
      z1 += expf((s1[m]-mx1)/TAU_);
    }
    lspec = pos0/TAU_ - (mx0/TAU_ + logf(z0));
    lspat = pos1/TAU_ - (mx1/TAU_ + logf(z1));
  }
  lspec = wave_reduce_sum(lspec);
  lspat = wave_reduce_sum(lspat);
  if (lane == 0) { bred[0][w]=lspec; bred[1][w]=lspat; }
  __syncthreads();
  if (tid == 0) {
    atomicAdd(&accums[0], bred[0][0]+bred[0][1]+bred[0][2]+bred[0][3]);
    atomicAdd(&accums[1], bred[1][0]+bred[1][1]+bred[1][2]+bred[1][3]);
  }
}

// ---------------- diversity regularizer ----------------
__global__ __launch_bounds__(64) void diversity_kernel(const float* __restrict__ K_spec, const float* __restrict__ K_spat,
                                 float* __restrict__ accums) {
  int route = blockIdx.x >> 3, h = blockIdx.x & 7;
  const float* Km = (route ? K_spat : K_spec) + h*16*64;
  int e = threadIdx.x;
  float s = 0.f, selfsum = 0.f;
  for (int m = 0; m < 16; ++m) {
    float x = Km[m*64 + e];
    float n2 = wave_reduce_sum(x*x);
    float p = x / fmaxf(sqrtf(n2), 1e-6f);
    s += p; selfsum += p*p;
  }
  float off = wave_reduce_sum(s*s - selfsum);
  if (e == 0) atomicAdd(&accums[2+route], off);
}

__global__ void zero_accums(float* accums){ if (threadIdx.x < 8) accums[threadIdx.x] = 0.f; }

__global__ void finalize_kernel(const float* __restrict__ accums, float* __restrict__ tail) {
  float loss_spec = -(accums[0] / (float)(B_*H_*N_));
  float loss_spat = -(accums[1] / (float)(B_*H_*N_));
  float contrastive = 0.5f*(loss_spec + loss_spat);
  float denom = (float)(H_*M_*(M_-1)) + 1e-6f;
  float diversity = 0.01f * (accums[2]/denom + accums[3]/denom);
  tail[0] = contrastive;
  tail[1] = diversity;
}

extern "C" void kernel_launch(void* const* d_in, const int* in_sizes, int n_in,
                              void* d_out, int out_size, void* d_ws, size_t ws_size,
                              hipStream_t stream) {
  const float* x       = (const float*)d_in[0];
  const float* W_qkv   = (const float*)d_in[1];
  const float* W_proj  = (const float*)d_in[2];
  const float* b_proj  = (const float*)d_in[3];
  const float* W_rspec = (const float*)d_in[4];
  const float* b_rspec = (const float*)d_in[5];
  const float* W_rspat = (const float*)d_in[6];
  const float* b_rspat = (const float*)d_in[7];
  const float* K_spec  = (const float*)d_in[8];
  const float* K_spat  = (const float*)d_in[9];
  const float* W_tok   = (const float*)d_in[10];
  const float* b_tok   = (const float*)d_in[11];
  const float* W_prot  = (const float*)d_in[12];
  const float* b_prot  = (const float*)d_in[13];
  float* out = (float*)d_out;

  float* ws = (float*)d_ws;
  float* qv       = ws;                 // 33,554,432 floats
  float* logits   = ws + 33554432;      // 8,388,608 (freed after router_topk)
  float* pctx     = ws + 33554432;      // overlays logits
  float* pZ       = ws + 37748736;      // overlays logits
  float* r_spec   = ws + 41943040;      // 4,194,304
  float* r_spat   = ws + 46137344;      // 4,194,304
  float* out_attn = ws + 33554432;      // overlays logits+pctx (consumed by then)
  float* ctxb     = ws + 50331648;
  float* pnorm    = ws + 50593792;
  float* accums   = ws + 50610176;

  dim3 blk256(256);

  // 1. router logits via MFMA (bias added in topk)
  gemm_mfma<<<dim3(256,1), blk256, 0, stream>>>(x, W_rspec, nullptr, logits,       512, 128, 256, 1<<30, 0);
  gemm_mfma<<<dim3(256,1), blk256, 0, stream>>>(x, W_rspat, nullptr, logits + 128, 512, 128, 256, 1<<30, 0);
  // 2. top-k masked softmax
  router_topk<<<2048, blk256, 0, stream>>>(logits, b_rspec, b_rspat, r_spec, r_spat);
  // 3. fused q+v GEMM
  gemm_mfma<<<dim3(256,8), blk256, 0, stream>>>(x, W_qkv, nullptr, qv, 512, 1536, 1024, 512, 512);
  // 4. context partial + reduce
  context_partial<<<1024, blk256, 0, stream>>>(r_spec, r_spat, K_spec, K_spat, qv, pctx, pZ);
  context_reduce<<<64, blk256, 0, stream>>>(pctx, pZ, ctxb);
  // 5. losses
  zero_accums<<<1, 64, 0, stream>>>(accums);
  protnorm_kernel<<<256, 64, 0, stream>>>(K_spec, K_spat, W_prot, b_prot, pnorm);
  contrastive_mfma<<<2048, blk256, 0, stream>>>(qv, r_spec, r_spat, W_tok, b_tok, pnorm, accums);
  diversity_kernel<<<16, 64, 0, stream>>>(K_spec, K_spat, accums);
  // 6. attention output
  attn_out_kernel<<<4096, blk256, 0, stream>>>(qv, ctxb, out_attn);
  // 7. final projection + bias
  gemm_mfma<<<dim3(256,4), blk256, 0, stream>>>(out_attn, W_proj, b_proj, out, 512, 512, 512, 1<<30, 0);
  // 8. scalars
  finalize_kernel<<<1, 1, 0, stream>>>(accums, out + 16777216);
}

// Round 5
// 529.214 us; speedup vs baseline: 7.1912x; 1.3734x over previous
//
#include <hip/hip_runtime.h>
#include <math.h>

#define B_ 8
#define N_ 4096
#define C_ 512
#define H_ 8
#define D_ 64
#define M_ 16
#define BN_TOK (B_*N_)
#define TAU_ 0.1f

typedef short s8v __attribute__((ext_vector_type(8)));
typedef float f4v __attribute__((ext_vector_type(4)));

__device__ __forceinline__ float wave_reduce_sum(float v){
  #pragma unroll
  for (int o = 32; o > 0; o >>= 1) v += __shfl_xor(v, o);
  return v;
}

__device__ __forceinline__ unsigned short f2b(float f){
  unsigned int u = __float_as_uint(f);
  u += 0x7fffu + ((u >> 16) & 1u);           // RNE
  return (unsigned short)(u >> 16);
}

__device__ __forceinline__ s8v pack8(const float* f){
  s8v r;
  #pragma unroll
  for (int e = 0; e < 8; ++e) r[e] = (short)f2b(f[e]);
  return r;
}

// ============ bf16-MFMA GEMM: C[M,N] = A_f32[M,K=512] * B_f32[512,N] (+bias) ============
__global__ __launch_bounds__(256) void gemm_mfma(const float* __restrict__ A, const float* __restrict__ Bw,
                          const float* __restrict__ bias, float* __restrict__ C,
                          int lda, int ldb, int ldc,
                          int skip_thresh, int skip_amt) {
  __shared__ __align__(16) unsigned short Asm[128*32];
  __shared__ __align__(16) unsigned short Bsm[128*32];
  const int tid = threadIdx.x;
  const int bm = blockIdx.x * 128;
  const int bn = blockIdx.y * 128;
  const int wcol0 = bn + (bn >= skip_thresh ? skip_amt : 0);

  const int lane = tid & 63, w = tid >> 6;
  const int w0 = (w >> 1) * 64, c0 = (w & 1) * 64;
  const int lm = lane & 15, lg = lane >> 4;
  const int xr = lg ^ (lm & 3);

  const int mA = tid >> 1, halfA = tid & 1;
  const int colB = tid & 127, khB = tid >> 7;

  f4v acc[4][4];
  #pragma unroll
  for (int i = 0; i < 4; ++i)
    #pragma unroll
    for (int j = 0; j < 4; ++j) acc[i][j] = (f4v){0.f,0.f,0.f,0.f};

  for (int k0 = 0; k0 < 512; k0 += 32) {
    const float4* ag = (const float4*)(A + (size_t)(bm + mA) * lda + k0 + 16 * halfA);
    float4 a0 = ag[0], a1 = ag[1], a2 = ag[2], a3 = ag[3];
    const float* bg = Bw + (size_t)(k0 + khB * 8) * ldb + wcol0 + colB;
    float fb[16];
    #pragma unroll
    for (int r = 0; r < 8; ++r) fb[r] = bg[(size_t)r * ldb];
    #pragma unroll
    for (int r = 0; r < 8; ++r) fb[8 + r] = bg[(size_t)(16 + r) * ldb];

    __syncthreads();
    {
      float fa[16] = {a0.x,a0.y,a0.z,a0.w, a1.x,a1.y,a1.z,a1.w,
                      a2.x,a2.y,a2.z,a2.w, a3.x,a3.y,a3.z,a3.w};
      int c1 = 2 * halfA, c2 = 2 * halfA + 1;
      *(s8v*)&Asm[mA*32 + ((c1 ^ (mA & 3)) << 3)] = pack8(&fa[0]);
      *(s8v*)&Asm[mA*32 + ((c2 ^ (mA & 3)) << 3)] = pack8(&fa[8]);
      int d1 = khB, d2 = khB + 2;
      *(s8v*)&Bsm[colB*32 + ((d1 ^ (colB & 3)) << 3)] = pack8(&fb[0]);
      *(s8v*)&Bsm[colB*32 + ((d2 ^ (colB & 3)) << 3)] = pack8(&fb[8]);
    }
    __syncthreads();

    s8v af[4], bf_[4];
    #pragma unroll
    for (int i = 0; i < 4; ++i) af[i]  = *(const s8v*)&Asm[(w0 + 16*i + lm)*32 + (xr << 3)];
    #pragma unroll
    for (int j = 0; j < 4; ++j) bf_[j] = *(const s8v*)&Bsm[(c0 + 16*j + lm)*32 + (xr << 3)];
    #pragma unroll
    for (int i = 0; i < 4; ++i)
      #pragma unroll
      for (int j = 0; j < 4; ++j)
        acc[i][j] = __builtin_amdgcn_mfma_f32_16x16x32_bf16(af[i], bf_[j], acc[i][j], 0, 0, 0);
  }

  #pragma unroll
  for (int j = 0; j < 4; ++j) {
    int cc = bn + c0 + 16*j + lm;
    float bj = bias ? bias[cc] : 0.f;
    #pragma unroll
    for (int i = 0; i < 4; ++i) {
      int row = bm + w0 + 16*i + lg*4;
      #pragma unroll
      for (int r = 0; r < 4; ++r)
        C[(size_t)(row + r) * ldc + cc] = acc[i][j][r] + bj;
    }
  }
}

// ---------------- router top-k + masked softmax ----------------
__global__ __launch_bounds__(256) void router_topk(const float* __restrict__ logits,
                            const float* __restrict__ b_rspec, const float* __restrict__ b_rspat,
                            float* __restrict__ r_spec, float* __restrict__ r_spat) {
  int t = blockIdx.x * blockDim.x + threadIdx.x;
  if (t >= BN_TOK * H_ * 2) return;
  int route = t & 1, h = (t >> 1) & 7, bn = t >> 4;
  int b = bn >> 12, n = bn & 4095;
  const float* lg = logits + (size_t)bn*256 + route*128 + h*16;
  const float* bias = (route ? b_rspat : b_rspec) + h*16;
  float v[16];
  #pragma unroll
  for (int m=0;m<16;++m) v[m] = lg[m] + bias[m];
  float m1=-1e30f, m2=-1e30f, m3=-1e30f;
  #pragma unroll
  for (int m=0;m<16;++m){
    float x=v[m];
    if (x>m1){m3=m2;m2=m1;m1=x;}
    else if (x>m2){m3=m2;m2=x;}
    else if (x>m3){m3=x;}
  }
  float S=0.f, Sm=0.f, e[16];
  #pragma unroll
  for (int m=0;m<16;++m){ e[m]=expf(v[m]-m1); S+=e[m]; if (v[m]>=m3) Sm+=e[m]; }
  float denom = fmaxf(Sm/S, 1e-6f);
  float inv = 1.f/(S*denom);
  float* r = (route ? r_spat : r_spec) + (((size_t)b*H_ + h)*N_ + n)*16;
  #pragma unroll
  for (int m=0;m<16;++m) r[m] = (v[m] >= m3) ? e[m]*inv : 0.f;
}

// ------- context via MFMA: per (b,h,chunk of 256 tokens) -------
// GEMM1: P[n][d] = exp( [r_spec|r_spat] @ [K_spec;K_spat] )  (k=32, one mfma/tile)
// Z[d] partial from C-fragments; P -> LDS (B-layout); GEMM2: ctx^T[e][d] = V^T @ P.
__global__ __launch_bounds__(256) void context_mfma(const float* __restrict__ r_spec, const float* __restrict__ r_spat,
                               const float* __restrict__ K_spec, const float* __restrict__ K_spat,
                               const float* __restrict__ qv, float* __restrict__ pctx, float* __restrict__ pZ) {
  const int chunk = blockIdx.x & 15, bh = blockIdx.x >> 4;
  const int b = bh >> 3, h = bh & 7;
  const int tid = threadIdx.x;
  const int lane = tid & 63, w = tid >> 6;
  const int lm = lane & 15, lg = lane >> 4;

  __shared__ __align__(16) unsigned short Kc[64*32];   // B1: [d][k=32] swz4
  __shared__ __align__(16) unsigned short Rs[64*32];   // A1: [n][k=32] swz4
  __shared__ __align__(16) unsigned short Vt[64*64];   // A2: [e][n]    swz8
  __shared__ __align__(16) unsigned short Ps[64*64];   // B2: [d][n]    swz8
  __shared__ float Zs[256];

  // stage K_cat once: d = tid&63, k-chunk c = tid>>6
  {
    int d = tid & 63, c = tid >> 6;
    float f[8];
    #pragma unroll
    for (int u = 0; u < 8; ++u) {
      int k = c*8 + u;
      f[u] = (k < 16) ? K_spec[h*1024 + k*64 + d] : K_spat[h*1024 + (k-16)*64 + d];
    }
    *(s8v*)&Kc[d*32 + ((c ^ (d&3)) << 3)] = pack8(f);
  }

  const float* rsg = r_spec + ((size_t)bh*N_ + chunk*256)*16;
  const float* rtg = r_spat + ((size_t)bh*N_ + chunk*256)*16;
  const float* vbase = qv + 512 + h*64;
  const size_t tokbase = (size_t)b*N_ + chunk*256;

  f4v acc2[4];
  #pragma unroll
  for (int j = 0; j < 4; ++j) acc2[j] = (f4v){0.f,0.f,0.f,0.f};
  float zreg[4] = {0.f,0.f,0.f,0.f};

  for (int t0 = 0; t0 < 4; ++t0) {
    __syncthreads();   // protect prev iter's LDS reads
    // stage R (A1): n = tid&63, chunk c = tid>>6 (c<2: spec m0-15, else spat)
    {
      int n = tid & 63, c = tid >> 6;
      const float* src = (c < 2 ? rsg : rtg) + ((size_t)(t0*64 + n))*16 + (c&1)*8;
      float f[8];
      float4 f0 = ((const float4*)src)[0], f1 = ((const float4*)src)[1];
      f[0]=f0.x; f[1]=f0.y; f[2]=f0.z; f[3]=f0.w; f[4]=f1.x; f[5]=f1.y; f[6]=f1.z; f[7]=f1.w;
      *(s8v*)&Rs[n*32 + ((c ^ (n&3)) << 3)] = pack8(f);
    }
    // stage V^T (A2): n = tid&63, e-quarter eq = tid>>6
    {
      int n = tid & 63, eq = tid >> 6;
      const float* src = vbase + (tokbase + t0*64 + n)*1024 + eq*16;
      float f[16];
      #pragma unroll
      for (int u = 0; u < 4; ++u) {
        float4 v4 = ((const float4*)src)[u];
        f[4*u]=v4.x; f[4*u+1]=v4.y; f[4*u+2]=v4.z; f[4*u+3]=v4.w;
      }
      #pragma unroll
      for (int u = 0; u < 16; ++u) {
        int e = eq*16 + u;
        Vt[e*64 + ((((n>>3) ^ (e&7)) << 3) | (n&7))] = f2b(f[u]);
      }
    }
    __syncthreads();
    // GEMM1: wave w = n-tile; exp; Z; write P to Ps (B-layout)
    {
      s8v a1 = *(const s8v*)&Rs[(16*w + lm)*32 + ((lg ^ (lm&3)) << 3)];
      #pragma unroll
      for (int j = 0; j < 4; ++j) {
        s8v b1 = *(const s8v*)&Kc[(16*j + lm)*32 + ((lg ^ (lm&3)) << 3)];
        f4v c1 = (f4v){0.f,0.f,0.f,0.f};
        c1 = __builtin_amdgcn_mfma_f32_16x16x32_bf16(a1, b1, c1, 0, 0, 0);
        float p0 = expf(c1[0]), p1 = expf(c1[1]), p2 = expf(c1[2]), p3 = expf(c1[3]);
        float zz = p0 + p1 + p2 + p3;
        zz += __shfl_xor(zz, 16); zz += __shfl_xor(zz, 32);
        zreg[j] += zz;
        int d = 16*j + lm;
        int n0w = 16*w + 4*lg;
        Ps[d*64 + (((((n0w  )>>3) ^ (d&7)) << 3) | ((n0w  )&7))] = f2b(p0);
        Ps[d*64 + (((((n0w+1)>>3) ^ (d&7)) << 3) | ((n0w+1)&7))] = f2b(p1);
        Ps[d*64 + (((((n0w+2)>>3) ^ (d&7)) << 3) | ((n0w+2)&7))] = f2b(p2);
        Ps[d*64 + (((((n0w+3)>>3) ^ (d&7)) << 3) | ((n0w+3)&7))] = f2b(p3);
      }
    }
    __syncthreads();
    // GEMM2: A = V^T (e-tile = w), B = P (d-tiles j), k = n = 64
    #pragma unroll
    for (int kb = 0; kb < 2; ++kb) {
      s8v a2 = *(const s8v*)&Vt[(16*w + lm)*64 + (((kb*4 + lg) ^ (lm&7)) << 3)];
      #pragma unroll
      for (int j = 0; j < 4; ++j) {
        s8v b2 = *(const s8v*)&Ps[(16*j + lm)*64 + (((kb*4 + lg) ^ (lm&7)) << 3)];
        acc2[j] = __builtin_amdgcn_mfma_f32_16x16x32_bf16(a2, b2, acc2[j], 0, 0, 0);
      }
    }
  }
  // write partial ctx^T [e][d] and Z partials
  float* pc = pctx + (size_t)(bh*16 + chunk)*4096;
  #pragma unroll
  for (int j = 0; j < 4; ++j) {
    #pragma unroll
    for (int r = 0; r < 4; ++r)
      pc[(16*w + 4*lg + r)*64 + 16*j + lm] = acc2[j][r];
    if (lg == 0) Zs[w*64 + 16*j + lm] = zreg[j];
  }
  __syncthreads();
  if (tid < 64)
    pZ[(size_t)(bh*16 + chunk)*64 + tid] = Zs[tid] + Zs[64+tid] + Zs[128+tid] + Zs[192+tid];
}

// ---- reduce partials: ctx^T[e][d] = sum_c pctx / Z[d] ----
__global__ __launch_bounds__(256) void context_reduce(const float* __restrict__ pctx, const float* __restrict__ pZ,
                              float* __restrict__ ctx) {
  const int bh = blockIdx.x;
  const int tid = threadIdx.x;
  const int e = tid >> 2, d0 = (tid & 3) * 16;
  float zs[16];
  #pragma unroll
  for (int j=0;j<16;++j) zs[j]=0.f;
  float s[16];
  #pragma unroll
  for (int j=0;j<16;++j) s[j]=0.f;
  for (int c = 0; c < 16; ++c) {
    const float* zp = pZ + (size_t)(bh*16 + c)*64 + d0;
    #pragma unroll
    for (int j=0;j<16;++j) zs[j] += zp[j];
    const float* pc = pctx + (size_t)(bh*16 + c)*4096 + e*64 + d0;
    #pragma unroll
    for (int j=0;j<16;++j) s[j] += pc[j];
  }
  float* co = ctx + (size_t)bh*4096 + e*64 + d0;
  #pragma unroll
  for (int j=0;j<16;++j) co[j] = s[j] / zs[j];
}

// ---------------- attention output via MFMA ----------------
// out[n][h*64+e] = q_h[n][:] @ ctx_h ; ctx stored transposed [e][d] = B-layout source
__global__ __launch_bounds__(256) void attn_mfma(const float* __restrict__ qv, const float* __restrict__ ctx,
                                float* __restrict__ out_attn) {
  const int tile = blockIdx.x;           // 256 tiles x 128 tokens
  const size_t g0 = (size_t)tile * 128;
  const int b = (int)(g0 >> 12);
  const int tid = threadIdx.x;
  const int lane = tid & 63, w = tid >> 6;
  const int lm = lane & 15, lg = lane >> 4;

  __shared__ __align__(16) unsigned short Aq[128*64];  // [n][d] swz8
  __shared__ __align__(16) unsigned short Bc[64*64];   // [e][d] swz8

  for (int h = 0; h < 8; ++h) {
    __syncthreads();
    // stage q slice: n = tid>>1, half = tid&1 (32 d each)
    {
      int n = tid >> 1, half = tid & 1;
      const float* src = qv + (g0 + n)*1024 + h*64 + half*32;
      float f[32];
      #pragma unroll
      for (int u = 0; u < 8; ++u) {
        float4 v4 = ((const float4*)src)[u];
        f[4*u]=v4.x; f[4*u+1]=v4.y; f[4*u+2]=v4.z; f[4*u+3]=v4.w;
      }
      #pragma unroll
      for (int cc = 0; cc < 4; ++cc)
        *(s8v*)&Aq[n*64 + (((half*4+cc) ^ (n&7)) << 3)] = pack8(&f[8*cc]);
    }
    // stage ctx^T: e = tid&63, kq = tid>>6 (16 d each)
    {
      int e = tid & 63, kq = tid >> 6;
      const float* src = ctx + (size_t)(b*8 + h)*4096 + e*64 + kq*16;
      float f[16];
      #pragma unroll
      for (int u = 0; u < 4; ++u) {
        float4 v4 = ((const float4*)src)[u];
        f[4*u]=v4.x; f[4*u+1]=v4.y; f[4*u+2]=v4.z; f[4*u+3]=v4.w;
      }
      *(s8v*)&Bc[e*64 + (((kq*2  ) ^ (e&7)) << 3)] = pack8(&f[0]);
      *(s8v*)&Bc[e*64 + (((kq*2+1) ^ (e&7)) << 3)] = pack8(&f[8]);
    }
    __syncthreads();
    f4v acc[2][4];
    #pragma unroll
    for (int i=0;i<2;++i)
      #pragma unroll
      for (int j=0;j<4;++j) acc[i][j] = (f4v){0.f,0.f,0.f,0.f};
    #pragma unroll
    for (int kb = 0; kb < 2; ++kb) {
      s8v bfr[4];
      #pragma unroll
      for (int j=0;j<4;++j) bfr[j] = *(const s8v*)&Bc[(16*j + lm)*64 + (((kb*4 + lg) ^ (lm&7)) << 3)];
      #pragma unroll
      for (int i=0;i<2;++i) {
        s8v afr = *(const s8v*)&Aq[(32*w + 16*i + lm)*64 + (((kb*4 + lg) ^ (lm&7)) << 3)];
        #pragma unroll
        for (int j=0;j<4;++j)
          acc[i][j] = __builtin_amdgcn_mfma_f32_16x16x32_bf16(afr, bfr[j], acc[i][j], 0, 0, 0);
      }
    }
    #pragma unroll
    for (int i=0;i<2;++i)
      #pragma unroll
      for (int j=0;j<4;++j)
        #pragma unroll
        for (int r=0;r<4;++r)
          out_attn[(g0 + 32*w + 16*i + 4*lg + r)*512 + h*64 + 16*j + lm] = acc[i][j][r];
  }
}

// ---------------- normalized prototypes ----------------
__global__ __launch_bounds__(64) void protnorm_kernel(const float* __restrict__ K_spec, const float* __restrict__ K_spat,
                               const float* __restrict__ W_prot, const float* __restrict__ b_prot,
                               float* __restrict__ pnorm) {
  int row = blockIdx.x;
  int route = row >> 7, hm = row & 127;
  const float* Km = (route ? K_spat : K_spec) + hm*64;
  int e = threadIdx.x;
  __shared__ float kv[64];
  kv[e] = Km[e];
  __syncthreads();
  float acc = b_prot[e];
  for (int dcol = 0; dcol < 64; ++dcol) acc = fmaf(kv[dcol], W_prot[dcol*64 + e], acc);
  float n2 = wave_reduce_sum(acc*acc);
  pnorm[(size_t)row*64 + e] = acc / fmaxf(sqrtf(n2), 1e-12f);
}

// ---------------- contrastive loss via MFMA ----------------
__global__ __launch_bounds__(256) void contrastive_mfma(const float* __restrict__ qv,
                                   const float* __restrict__ r_spec, const float* __restrict__ r_spat,
                                   const float* __restrict__ W_tok, const float* __restrict__ b_tok,
                                   const float* __restrict__ pnorm, float* __restrict__ accums) {
  const int tile = blockIdx.x & 255;
  const int h = blockIdx.x >> 8;
  const int t0 = tile * 128;
  const int b = t0 >> 12;
  const int n0 = t0 & 4095;
  const int tid = threadIdx.x;
  const int lane = tid & 63, w = tid >> 6;
  const int lm = lane & 15, lg = lane >> 4;

  __shared__ __align__(16) unsigned short Vsm[128*72];
  __shared__ __align__(16) unsigned short Wsm[64*72];
  __shared__ __align__(16) unsigned short Psm[32*72];
  __shared__ __align__(16) unsigned short Tsm[128*72];
  __shared__ float Ssm[128*36];
  __shared__ float nrmS[128];
  __shared__ float btkS[64];
  __shared__ float bred[2][4];

  {
    const int vr = tid >> 1, vh = tid & 1;
    const float* vg = qv + (size_t)(b*N_ + n0 + vr)*1024 + 512 + h*64 + vh*32;
    float f[32];
    #pragma unroll
    for (int i = 0; i < 8; ++i) {
      float4 v4 = ((const float4*)vg)[i];
      f[4*i]=v4.x; f[4*i+1]=v4.y; f[4*i+2]=v4.z; f[4*i+3]=v4.w;
    }
    #pragma unroll
    for (int c = 0; c < 4; ++c) *(s8v*)&Vsm[vr*72 + vh*32 + c*8] = pack8(&f[8*c]);
  }
  {
    const int e = tid & 63, kh = tid >> 6;
    float f[16];
    #pragma unroll
    for (int rr = 0; rr < 16; ++rr) f[rr] = W_tok[(size_t)(kh*16+rr)*64 + e];
    *(s8v*)&Wsm[e*72 + kh*16]     = pack8(&f[0]);
    *(s8v*)&Wsm[e*72 + kh*16 + 8] = pack8(&f[8]);
  }
  if (tid < 128) {
    const int proto = tid >> 2, q4 = tid & 3;
    const int src = (proto < 16) ? (h*16 + proto) : (128 + h*16 + (proto-16));
    const float* pg = pnorm + (size_t)src*64 + q4*16;
    float f[16];
    #pragma unroll
    for (int i = 0; i < 4; ++i) {
      float4 v4 = ((const float4*)pg)[i];
      f[4*i]=v4.x; f[4*i+1]=v4.y; f[4*i+2]=v4.z; f[4*i+3]=v4.w;
    }
    *(s8v*)&Psm[proto*72 + q4*16]     = pack8(&f[0]);
    *(s8v*)&Psm[proto*72 + q4*16 + 8] = pack8(&f[8]);
  }
  if (tid < 64) btkS[tid] = b_tok[tid];
  __syncthreads();

  f4v acc[2][4];
  #pragma unroll
  for (int i=0;i<2;++i)
    #pragma unroll
    for (int j=0;j<4;++j) acc[i][j] = (f4v){0.f,0.f,0.f,0.f};
  {
    s8v bf0[4], bf1[4];
    #pragma unroll
    for (int j=0;j<4;++j) {
      bf0[j] = *(const s8v*)&Wsm[(j*16+lm)*72 + lg*8];
      bf1[j] = *(const s8v*)&Wsm[(j*16+lm)*72 + 32 + lg*8];
    }
    #pragma unroll
    for (int i=0;i<2;++i) {
      s8v af0 = *(const s8v*)&Vsm[(w*32+16*i+lm)*72 + lg*8];
      s8v af1 = *(const s8v*)&Vsm[(w*32+16*i+lm)*72 + 32 + lg*8];
      #pragma unroll
      for (int j=0;j<4;++j) {
        acc[i][j] = __builtin_amdgcn_mfma_f32_16x16x32_bf16(af0, bf0[j], acc[i][j], 0, 0, 0);
        acc[i][j] = __builtin_amdgcn_mfma_f32_16x16x32_bf16(af1, bf1[j], acc[i][j], 0, 0, 0);
      }
    }
  }
  #pragma unroll
  for (int i=0;i<2;++i) {
    #pragma unroll
    for (int r=0;r<4;++r) {
      float s = 0.f;
      #pragma unroll
      for (int j=0;j<4;++j) {
        float val = acc[i][j][r] + btkS[j*16+lm];
        acc[i][j][r] = val;
        s += val*val;
      }
      s += __shfl_xor(s,1); s += __shfl_xor(s,2); s += __shfl_xor(s,4); s += __shfl_xor(s,8);
      if (lm == 0) nrmS[w*32 + 16*i + lg*4 + r] = s;
    }
  }
  #pragma unroll
  for (int i=0;i<2;++i)
    #pragma unroll
    for (int j=0;j<4;++j)
      #pragma unroll
      for (int r=0;r<4;++r)
        Tsm[(w*32+16*i+lg*4+r)*72 + j*16+lm] = f2b(acc[i][j][r]);
  __syncthreads();

  f4v acc2[2][2];
  #pragma unroll
  for (int i=0;i<2;++i)
    #pragma unroll
    for (int j=0;j<2;++j) acc2[i][j] = (f4v){0.f,0.f,0.f,0.f};
  {
    s8v bf0[2], bf1[2];
    #pragma unroll
    for (int j=0;j<2;++j) {
      bf0[j] = *(const s8v*)&Psm[(j*16+lm)*72 + lg*8];
      bf1[j] = *(const s8v*)&Psm[(j*16+lm)*72 + 32 + lg*8];
    }
    #pragma unroll
    for (int i=0;i<2;++i) {
      s8v af0 = *(const s8v*)&Tsm[(w*32+16*i+lm)*72 + lg*8];
      s8v af1 = *(const s8v*)&Tsm[(w*32+16*i+lm)*72 + 32 + lg*8];
      #pragma unroll
      for (int j=0;j<2;++j) {
        acc2[i][j] = __builtin_amdgcn_mfma_f32_16x16x32_bf16(af0, bf0[j], acc2[i][j], 0, 0, 0);
        acc2[i][j] = __builtin_amdgcn_mfma_f32_16x16x32_bf16(af1, bf1[j], acc2[i][j], 0, 0, 0);
      }
    }
  }
  #pragma unroll
  for (int i=0;i<2;++i)
    #pragma unroll
    for (int j=0;j<2;++j)
      #pragma unroll
      for (int r=0;r<4;++r)
        Ssm[(w*32+16*i+lg*4+r)*36 + j*16+lm] = acc2[i][j][r];
  __syncthreads();

  float lspec = 0.f, lspat = 0.f;
  if (tid < 128) {
    const int tt = tid;
    float inv = 1.f / fmaxf(sqrtf(nrmS[tt]), 1e-12f);
    const float* rsg = r_spec + (((size_t)b*H_ + h)*N_ + n0 + tt)*16;
    const float* rtg = r_spat + (((size_t)b*H_ + h)*N_ + n0 + tt)*16;
    float s0[16], s1[16];
    #pragma unroll
    for (int m=0;m<16;++m) { s0[m] = Ssm[tt*36 + m]*inv; s1[m] = Ssm[tt*36 + 16 + m]*inv; }
    float pos0=0.f, pos1=0.f, mx0=-1e30f, mx1=-1e30f;
    #pragma unroll
    for (int m=0;m<16;++m) {
      pos0 += s0[m]*rsg[m];
      pos1 += s1[m]*rtg[m];
      mx0 = fmaxf(mx0, s0[m]);
      mx1 = fmaxf(mx1, s1[m]);
    }
    float z0=0.f, z1=0.f;
    #pragma unroll
    for (int m=0;m<16;++m) {
      z0 += expf((s0[m]-mx0)/TAU_);
      z1 += expf((s1[m]-mx1)/TAU_);
    }
    lspec = pos0/TAU_ - (mx0/TAU_ + logf(z0));
    lspat = pos1/TAU_ - (mx1/TAU_ + logf(z1));
  }
  lspec = wave_reduce_sum(lspec);
  lspat = wave_reduce_sum(lspat);
  if (lane == 0) { bred[0][w]=lspec; bred[1][w]=lspat; }
  __syncthreads();
  if (tid == 0) {
    atomicAdd(&accums[0], bred[0][0]+bred[0][1]+bred[0][2]+bred[0][3]);
    atomicAdd(&accums[1], bred[1][0]+bred[1][1]+bred[1][2]+bred[1][3]);
  }
}

// ---------------- diversity regularizer ----------------
__global__ __launch_bounds__(64) void diversity_kernel(const float* __restrict__ K_spec, const float* __restrict__ K_spat,
                                 float* __restrict__ accums) {
  int route = blockIdx.x >> 3, h = blockIdx.x & 7;
  const float* Km = (route ? K_spat : K_spec) + h*16*64;
  int e = threadIdx.x;
  float s = 0.f, selfsum = 0.f;
  for (int m = 0; m < 16; ++m) {
    float x = Km[m*64 + e];
    float n2 = wave_reduce_sum(x*x);
    float p = x / fmaxf(sqrtf(n2), 1e-6f);
    s += p; selfsum += p*p;
  }
  float off = wave_reduce_sum(s*s - selfsum);
  if (e == 0) atomicAdd(&accums[2+route], off);
}

__global__ void zero_accums(float* accums){ if (threadIdx.x < 8) accums[threadIdx.x] = 0.f; }

__global__ void finalize_kernel(const float* __restrict__ accums, float* __restrict__ tail) {
  float loss_spec = -(accums[0] / (float)(B_*H_*N_));
  float loss_spat = -(accums[1] / (float)(B_*H_*N_));
  float contrastive = 0.5f*(loss_spec + loss_spat);
  float denom = (float)(H_*M_*(M_-1)) + 1e-6f;
  float diversity = 0.01f * (accums[2]/denom + accums[3]/denom);
  tail[0] = contrastive;
  tail[1] = diversity;
}

extern "C" void kernel_launch(void* const* d_in, const int* in_sizes, int n_in,
                              void* d_out, int out_size, void* d_ws, size_t ws_size,
                              hipStream_t stream) {
  const float* x       = (const float*)d_in[0];
  const float* W_qkv   = (const float*)d_in[1];
  const float* W_proj  = (const float*)d_in[2];
  const float* b_proj  = (const float*)d_in[3];
  const float* W_rspec = (const float*)d_in[4];
  const float* b_rspec = (const float*)d_in[5];
  const float* W_rspat = (const float*)d_in[6];
  const float* b_rspat = (const float*)d_in[7];
  const float* K_spec  = (const float*)d_in[8];
  const float* K_spat  = (const float*)d_in[9];
  const float* W_tok   = (const float*)d_in[10];
  const float* b_tok   = (const float*)d_in[11];
  const float* W_prot  = (const float*)d_in[12];
  const float* b_prot  = (const float*)d_in[13];
  float* out = (float*)d_out;

  float* ws = (float*)d_ws;
  float* qv       = ws;                 // 33,554,432 floats
  float* logits   = ws + 33554432;      // (freed after router_topk)
  float* pctx     = ws + 33554432;      // overlays logits
  float* pZ       = ws + 37748736;      // overlays logits
  float* r_spec   = ws + 41943040;
  float* r_spat   = ws + 46137344;
  float* out_attn = ws + 33554432;      // overlays logits+pctx+r (consumed by then)
  float* ctxb     = ws + 50331648;      // [bh][e][d]  (transposed!)
  float* pnorm    = ws + 50593792;
  float* accums   = ws + 50610176;

  dim3 blk256(256);

  // 1. router logits via MFMA (bias added in topk)
  gemm_mfma<<<dim3(256,1), blk256, 0, stream>>>(x, W_rspec, nullptr, logits,       512, 128, 256, 1<<30, 0);
  gemm_mfma<<<dim3(256,1), blk256, 0, stream>>>(x, W_rspat, nullptr, logits + 128, 512, 128, 256, 1<<30, 0);
  // 2. top-k masked softmax
  router_topk<<<2048, blk256, 0, stream>>>(logits, b_rspec, b_rspat, r_spec, r_spat);
  // 3. fused q+v GEMM
  gemm_mfma<<<dim3(256,8), blk256, 0, stream>>>(x, W_qkv, nullptr, qv, 512, 1536, 1024, 512, 512);
  // 4. context via MFMA: partials then reduce (ctx stored transposed [e][d])
  context_mfma<<<1024, blk256, 0, stream>>>(r_spec, r_spat, K_spec, K_spat, qv, pctx, pZ);
  context_reduce<<<64, blk256, 0, stream>>>(pctx, pZ, ctxb);
  // 5. losses
  zero_accums<<<1, 64, 0, stream>>>(accums);
  protnorm_kernel<<<256, 64, 0, stream>>>(K_spec, K_spat, W_prot, b_prot, pnorm);
  contrastive_mfma<<<2048, blk256, 0, stream>>>(qv, r_spec, r_spat, W_tok, b_tok, pnorm, accums);
  diversity_kernel<<<16, 64, 0, stream>>>(K_spec, K_spat, accums);
  // 6. attention output via MFMA (overlays r — contrastive already consumed it)
  attn_mfma<<<256, blk256, 0, stream>>>(qv, ctxb, out_attn);
  // 7. final projection + bias
  gemm_mfma<<<dim3(256,4), blk256, 0, stream>>>(out_attn, W_proj, b_proj, out, 512, 512, 512, 1<<30, 0);
  // 8. scalars
  finalize_kernel<<<1, 1, 0, stream>>>(accums, out + 16777216);
}